// Round 9
// baseline (184.818 us; speedup 1.0000x reference)
//
#include <hip/hip_runtime.h>
#include <hip/hip_bf16.h>
#include <stdint.h>

// Problem constants: x[2,2048,1024], H=16, Dh=64
#define MROWS 4096   // B*T
#define DMODEL 1024
#define NQKV 3072
#define TSEQ 2048

typedef __attribute__((ext_vector_type(8))) short short8;   // 8 bf16 = 4 VGPRs
typedef __attribute__((ext_vector_type(4))) short short4v;  // 4 bf16 = 2 VGPRs
typedef __attribute__((ext_vector_type(4))) float floatx4;  // MFMA C/D
typedef unsigned short ushort_t;

// K/V tiled layouts for glds staging: [bh][32 tiles][64 rows][72] bf16.
#define TILE_ELEMS 4608        // 64*72
#define BH_TILE_STRIDE 147456  // 32*4608

// Q pre-scale: (1/sqrt(64)) * log2(e) -- attention softmax runs in base 2.
#define QSCALE 0.1803368801111204f

static __device__ __forceinline__ unsigned short f2bf(float f) {
    union { float f; unsigned u; } v; v.f = f;
    unsigned r = v.u + 0x7fff + ((v.u >> 16) & 1);   // RNE
    return (unsigned short)(r >> 16);
}

// --- target-specific intrinsic wrappers -------------------------------------
// hipcc compiles this TU twice (device gfx950 + host x86). Host pass must
// PARSE device code but never executes it; gate amdgcn-only builtins on
// __HIP_DEVICE_COMPILE__ so the host pass gets plain-C fallbacks.

// D = A*B + C, 16x16x16 bf16 (A,B: 4 bf16/lane; C/D: 4 fp32/lane)
static __device__ __forceinline__ floatx4 mfma16(short4v a, short4v b, floatx4 c) {
#if defined(__HIP_DEVICE_COMPILE__)
#if __has_builtin(__builtin_amdgcn_mfma_f32_16x16x16bf16_1k)
    return __builtin_amdgcn_mfma_f32_16x16x16bf16_1k(a, b, c, 0, 0, 0);
#else
#error "mfma 16x16x16 bf16 builtin unavailable on device"
#endif
#else
    return c;   // host pass: parse-only, never executed
#endif
}

// pack two fp32 -> two bf16 (round-half-up): low16 = bf16(a), high16 = bf16(b).
static __device__ __forceinline__ unsigned pk2bf(float a, float b) {
    unsigned ua = __float_as_uint(a) + 0x8000u;
    unsigned ub = __float_as_uint(b) + 0x8000u;
#if defined(__HIP_DEVICE_COMPILE__) && __has_builtin(__builtin_amdgcn_perm)
    return __builtin_amdgcn_perm(ub, ua, 0x07060302u);  // {ub.b3,ub.b2,ua.b3,ua.b2}
#else
    return (ua >> 16) | (ub & 0xFFFF0000u);
#endif
}

// pack two fp32 -> two bf16 via the HW packed converter (RNE), 1 instr vs 3.
static __device__ __forceinline__ unsigned cvtpk(float a, float b) {
#if defined(__HIP_DEVICE_COMPILE__)
    unsigned r;
    asm("v_cvt_pk_bf16_f32 %0, %1, %2" : "=v"(r) : "v"(a), "v"(b));
    return r;
#else
    return pk2bf(a, b);   // host pass: parse-only
#endif
}

static __device__ __forceinline__ float exp2_fast(float x) {
#if defined(__HIP_DEVICE_COMPILE__) && __has_builtin(__builtin_amdgcn_exp2f)
    return __builtin_amdgcn_exp2f(x);
#else
    return exp2f(x);
#endif
}

// async global->LDS, 16B per lane. Global addr must be PER-LANE; LDS dest is
// wave-uniform base + lane*16.
static __device__ __forceinline__ void glds16(const void* g, void* l) {
    __builtin_amdgcn_global_load_lds(
        (const __attribute__((address_space(1))) void*)g,
        (__attribute__((address_space(3))) void*)l, 16, 0, 0);
}

// ---------------- cast fp32 -> bf16 (n multiple of 4) ----------------
__global__ void cast_f32_bf16(const float* __restrict__ in,
                              ushort_t* __restrict__ out, int n) {
    int i = (blockIdx.x * blockDim.x + threadIdx.x) * 4;
    if (i < n) {
        float4 f = *(const float4*)(in + i);
        ushort4 o;
        o.x = f2bf(f.x); o.y = f2bf(f.y); o.z = f2bf(f.z); o.w = f2bf(f.w);
        *(ushort4*)(out + i) = o;
    }
}

// ---------------- transpose + cast: in[R][C] f32 -> out[C][R] bf16 ----------------
__global__ void transpose_cast(const float* __restrict__ in,
                               ushort_t* __restrict__ out, int R, int C) {
    __shared__ float tile[32][33];
    int c0 = blockIdx.x * 32, r0 = blockIdx.y * 32;
    int tx = threadIdx.x & 31, ty = threadIdx.x >> 5;
    for (int i = 0; i < 4; i++) {
        int r = ty + i * 8;
        tile[r][tx] = in[(size_t)(r0 + r) * C + c0 + tx];
    }
    __syncthreads();
    for (int i = 0; i < 4; i++) {
        int r = ty + i * 8;
        out[(size_t)(c0 + r) * R + r0 + tx] = f2bf(tile[tx][r]);
    }
}

// ---------------- V transpose (FALLBACK PATH ONLY): Vb -> Vt tiled ----------
__global__ void transpose_v(const ushort_t* __restrict__ in,
                            ushort_t* __restrict__ out) {
    __shared__ ushort_t T[64][72];
    int tile = blockIdx.x, bh = blockIdx.y;
    int tid = threadIdx.x;
    int row = tid >> 2, q4 = tid & 3;
    const ushort_t* ip = in + ((size_t)bh * TSEQ + tile * 64) * 64;
#pragma unroll
    for (int p = 0; p < 2; p++) {
        int c = q4 * 16 + p * 8;
        *(uint4*)(&T[row][c]) = *(const uint4*)(ip + (size_t)row * 64 + c);
    }
    __syncthreads();
    ushort_t* op = out + (size_t)bh * BH_TILE_STRIDE + (size_t)tile * TILE_ELEMS;
#pragma unroll
    for (int p = 0; p < 2; p++) {
        int cbase = q4 * 16 + p * 8;          // c' chunk base
        ushort_t tmp[8];
#pragma unroll
        for (int e = 0; e < 8; e++) {
            int cp = cbase + e;               // c' = 16*Q + 4*SB + J
            int Q = cp >> 4, SB = (cp >> 2) & 3, J = cp & 3;
            int s = SB * 16 + Q * 4 + J;
            tmp[e] = T[s][row];               // row = d
        }
        *(uint4*)(op + (size_t)row * 72 + cbase) = *(uint4*)tmp;
    }
}

// ---------------- GEMM (dbuf 2-phase, BK=32), XCD-swizzled 1-D grid ----------
// C = A[M][K] @ Bt[N][K]^T + bias.  (round-6 proven version, 180.7 us x2)
// T3-minimum recipe: double-buffered LDS, prefetch of tile k+32 ISSUED BEFORE
// the ds_read+MFMA of tile k, single __syncthreads per K-step. Round-8 showed
// deeper pipelining (3-buffer counted vmcnt) is NEUTRAL -> the stall is gone;
// QKV is LDS-port/work-bound at this wave-tile shape. Structural floor here.
// Block mapping: id -> xcd = id&7, each XCD owns PERXCD consecutive m-tiles.
// EPI 0: fp32 out0[M][N] + bias.
// EPI 1: Q -> [bh][t][64] bf16 *QSCALE; K -> tiled; V -> tiled-permuted direct.
// EPI 2: like EPI 1 but V linear (fallback, feeds transpose_v).
template <int EPI, int MFRAG, int PERXCD>
__global__ __launch_bounds__(256, 3)
void gemm_glds(const ushort_t* __restrict__ A,
               const ushort_t* __restrict__ Bt,
               const float* __restrict__ bias,
               void* __restrict__ out0, void* __restrict__ out1, void* __restrict__ out2,
               int M, int N, int K) {
    __shared__ ushort_t As[2][MFRAG * 32 * 32];
    __shared__ ushort_t Bs[2][128 * 32];
    int tid = threadIdx.x;
    int wave = tid >> 6, lane = tid & 63;
    int quad = lane >> 4, l16 = lane & 15;
    // XCD swizzle (PERXCD is a power of two)
    int id = blockIdx.x;
    int xcd = id & 7, sidx = id >> 3;
    int m_idx = xcd * PERXCD + (sidx & (PERXCD - 1));
    int n_idx = sidx / PERXCD;
    int m0 = m_idx * (MFRAG * 32), n0 = n_idx * 128;
    int wm = (wave & 1) * (MFRAG * 16), wn = (wave >> 1) * 64;

    const floatx4 zero = {0.f, 0.f, 0.f, 0.f};
    floatx4 acc[MFRAG][4];
#pragma unroll
    for (int i = 0; i < MFRAG; i++)
#pragma unroll
        for (int j = 0; j < 4; j++) acc[i][j] = zero;

    int srow = tid >> 2, sc = tid & 3;
    const ushort_t* ag = A  + (size_t)(m0 + srow) * K + sc * 8;
    const ushort_t* bg = Bt + (size_t)(n0 + srow) * K + sc * 8;
    int woff = wave * 512;

    // prologue: stage tile 0 into buffer 0, drain, then loop with prefetch
    glds16(ag, &As[0][woff]);
    if (MFRAG == 4) glds16(ag + (size_t)64 * K, &As[0][woff + 2048]);
    glds16(bg, &Bs[0][woff]);
    glds16(bg + (size_t)64 * K, &Bs[0][woff + 2048]);
    __syncthreads();

    int cur = 0;
    for (int k0 = 0; k0 < K; k0 += 32) {
        if (k0 + 32 < K) {
            int nb = cur ^ 1, kn = k0 + 32;
            glds16(ag + kn, &As[nb][woff]);
            if (MFRAG == 4) glds16(ag + (size_t)64 * K + kn, &As[nb][woff + 2048]);
            glds16(bg + kn, &Bs[nb][woff]);
            glds16(bg + (size_t)64 * K + kn, &Bs[nb][woff + 2048]);
        }
        short8 af[MFRAG], bf[4];
#pragma unroll
        for (int i = 0; i < MFRAG; i++)
            af[i] = *(const short8*)(&As[cur][(wm + i * 16 + l16) * 32 + quad * 8]);
#pragma unroll
        for (int j = 0; j < 4; j++)
            bf[j] = *(const short8*)(&Bs[cur][(wn + j * 16 + l16) * 32 + quad * 8]);
#pragma unroll
        for (int i = 0; i < MFRAG; i++)
#pragma unroll
            for (int j = 0; j < 4; j++)
                acc[i][j] = __builtin_amdgcn_mfma_f32_16x16x32_bf16(
                    af[i], bf[j], acc[i][j], 0, 0, 0);
        __syncthreads();   // emits vmcnt(0) lgkmcnt(0): prefetch has had
        cur ^= 1;          // the whole MFMA block to land
    }

    int sec = n0 >> 10;   // block-uniform (EPI!=0): 0=Q, 1=K, 2=V
    ushort_t* dst = (ushort_t*)(sec == 0 ? out0 : (sec == 1 ? out1 : out2));

    if (EPI == 1 && sec == 2) {
        // V -> tiled-permuted Vt, one 8B store per fragment
#pragma unroll
        for (int i = 0; i < MFRAG; i++) {
            int row = m0 + wm + i * 16 + quad * 4;
            int Abits = ((wm >> 4) + i) & 3;        // SB of s = t_local
            int b = row >> 11, t = row & 2047;
            int tile = t >> 6;
            int colp = 16 * quad + 4 * Abits;       // col' base; r adds 0..3
#pragma unroll
            for (int j = 0; j < 4; j++) {
                int col = n0 + wn + j * 16 + l16;
                int within = col & 1023, h = within >> 6, d = within & 63;
                size_t bh = (size_t)(b * 16 + h);
                float bvs = bias[col];
                ushort4 o;
                o.x = f2bf(acc[i][j][0] + bvs);
                o.y = f2bf(acc[i][j][1] + bvs);
                o.z = f2bf(acc[i][j][2] + bvs);
                o.w = f2bf(acc[i][j][3] + bvs);
                *(ushort4*)(dst + bh * BH_TILE_STRIDE + (size_t)tile * TILE_ELEMS
                            + (size_t)d * 72 + colp) = o;
            }
        }
        return;
    }

#pragma unroll
    for (int i = 0; i < MFRAG; i++) {
        int row = m0 + wm + i * 16 + quad * 4;
#pragma unroll
        for (int j = 0; j < 4; j++) {
            int col = n0 + wn + j * 16 + l16;
            float bvs = bias[col];
#pragma unroll
            for (int r = 0; r < 4; r++) {
                float v = acc[i][j][r] + bvs;
                int rowr = row + r;
                if (EPI == 0) {
                    ((float*)out0)[(size_t)rowr * N + col] = v;
                } else {
                    int b = rowr >> 11, t = rowr & 2047;
                    int within = col & 1023, h = within >> 6, d = within & 63;
                    size_t bh = (size_t)(b * 16 + h);
                    if (sec == 0)
                        dst[(bh * 2048 + t) * 64 + d] = f2bf(v * QSCALE);
                    else if (sec == 1)
                        dst[bh * BH_TILE_STRIDE + (size_t)(t >> 6) * TILE_ELEMS
                            + (size_t)(t & 63) * 72 + d] = f2bf(v);
                    else
                        dst[(bh * 2048 + t) * 64 + d] = f2bf(v);   // EPI==2 linear V
                }
            }
        }
    }
}

// ---------------- flash attention, merged-key-stream blocks, 2-wave ----------
// Round-9 change: sub0 previously ran TWO sequential segments both streaming
// keys from tile 0 (q-tile p keys 0..p, then q-tile 31-p keys 0..15-p; 17
// steps). Merged: ONE key stream of cnt = max(p+1, 16-p) steps (9..16)
// computing BOTH q-tiles per step while in range -- K/V staged and read once
// for the overlap. Steps: 17 -> avg 12.5 (-26% sub0, -14% overall); max block
// length 17 -> 16 (balance strictly improves). MFMA work unchanged; removes
// per-step overhead (barrier, glds issue, ds_read chains).
// sub1 unchanged: q-tile 31-p, keys 16-p..31-p -> fp32 partial B.
// Base-2 softmax, no max-shift: partials merge by addition.
// attn_combine does (O_A+O_B)/(l_A+l_B) for the upper 1024 rows.
// XCD-affine: id&7 -> XCD, 4 bh per XCD (K/V L2-resident; FETCH 139->13 MB).
__global__ __launch_bounds__(128, 2)
void attn_split(const ushort_t* __restrict__ Qb,
                const ushort_t* __restrict__ Kt,
                const ushort_t* __restrict__ Vt,
                ushort_t* __restrict__ outb,
                float* __restrict__ PO_a, float* __restrict__ PO_b,
                float* __restrict__ Pl_a, float* __restrict__ Pl_b) {
    __shared__ ushort_t Ks[2][64 * 72];
    __shared__ ushort_t Vs[2][64 * 72];
    int tid = threadIdx.x;
    int wave = tid >> 6, lane = tid & 63;   // wave 0..1
    int quad = lane >> 4, l16 = lane & 15;
    int id = blockIdx.x;                  // 0..1023
    int g = id >> 3;                      // 0..127
    int bh = (id & 7) * 4 + (g >> 5);     // XCD-affine: id&7 -> XCD, 4 bh/XCD
    int rem = g & 31;
    int p = rem >> 1, sub = rem & 1;      // pair 0..15, sub-block 0/1
    int b = bh >> 4, h = bh & 15;
    const ushort_t* qh = Qb + (size_t)bh * TSEQ * 64;
    const ushort_t* kh = Kt + (size_t)bh * BH_TILE_STRIDE;
    const ushort_t* vh = Vt + (size_t)bh * BH_TILE_STRIDE;
    const floatx4 zero = {0.f, 0.f, 0.f, 0.f};
    const short4v ones = {(short)0x3F80, (short)0x3F80, (short)0x3F80, (short)0x3F80};
    int lo8 = lane * 8;   // per-lane 16B offset for glds global addresses

    if (sub == 0) {
        // ---- merged dual-q-tile block: qtA = p (keys 0..p, final write),
        //      qtB = 31-p (keys 0..15-p, fp32 partial A) ----
        int qtA = p, qtB = 31 - p;
        int limA = p, limB = 15 - p;                 // inclusive key-tile limits
        int cnt = (limA > limB ? limA : limB) + 1;   // 9..16 steps

        short8 qAf0[2], qAf1[2], qBf0[2], qBf1[2];
#pragma unroll
        for (int qs = 0; qs < 2; qs++) {
            int rA = qtA * 64 + wave * 32 + qs * 16 + l16;
            int rB = qtB * 64 + wave * 32 + qs * 16 + l16;
            qAf0[qs] = *(const short8*)(qh + (size_t)rA * 64 + quad * 8);
            qAf1[qs] = *(const short8*)(qh + (size_t)rA * 64 + 32 + quad * 8);
            qBf0[qs] = *(const short8*)(qh + (size_t)rB * 64 + quad * 8);
            qBf1[qs] = *(const short8*)(qh + (size_t)rB * 64 + 32 + quad * 8);
        }

        floatx4 OA[2][4], OB[2][4], lA[2], lB[2];
#pragma unroll
        for (int qs = 0; qs < 2; qs++) {
            lA[qs] = zero; lB[qs] = zero;
#pragma unroll
            for (int j = 0; j < 4; j++) { OA[qs][j] = zero; OB[qs][j] = zero; }
        }

        // preload tile 0 -> buffer 0 (9 KB each = 9 x 1KB glds, 2 waves)
#pragma unroll
        for (int c = 0; c < 5; c++) {
            int cc = wave + 2 * c;
            if (cc < 9) {
                glds16(kh + cc * 512 + lo8, &Ks[0][cc * 512]);
                glds16(vh + cc * 512 + lo8, &Vs[0][cc * 512]);
            }
        }

        for (int s = 0; s < cnt; s++) {
            int cur = s & 1;
            __syncthreads();
            if (s + 1 < cnt) {
                const ushort_t* kt = kh + (size_t)(s + 1) * TILE_ELEMS;
                const ushort_t* vt = vh + (size_t)(s + 1) * TILE_ELEMS;
#pragma unroll
                for (int c = 0; c < 5; c++) {
                    int cc = wave + 2 * c;
                    if (cc < 9) {
                        glds16(kt + cc * 512 + lo8, &Ks[cur ^ 1][cc * 512]);
                        glds16(vt + cc * 512 + lo8, &Vs[cur ^ 1][cc * 512]);
                    }
                }
            }
            const ushort_t* ks = &Ks[cur][0];
            const ushort_t* vs = &Vs[cur][0];
            bool doA = (s <= limA), doB = (s <= limB);   // block-uniform

            // --- tile A through pfA (transients SA die before SB is born) ---
            short4v pfA[2][4], pfB[2][4];
            if (doA) {
                floatx4 SA[2][4];
                __builtin_amdgcn_s_setprio(1);
#pragma unroll
                for (int sb = 0; sb < 4; sb++) {
                    short8 kf0 = *(const short8*)(ks + (sb * 16 + l16) * 72 + quad * 8);
                    short8 kf1 = *(const short8*)(ks + (sb * 16 + l16) * 72 + 32 + quad * 8);
#pragma unroll
                    for (int qs = 0; qs < 2; qs++) {
                        floatx4 t = zero;
                        t = __builtin_amdgcn_mfma_f32_16x16x32_bf16(kf0, qAf0[qs], t, 0, 0, 0);
                        t = __builtin_amdgcn_mfma_f32_16x16x32_bf16(kf1, qAf1[qs], t, 0, 0, 0);
                        SA[qs][sb] = t;
                    }
                }
                __builtin_amdgcn_s_setprio(0);
                if (s == limA) {   // diagonal of qtA (key-tile s == qtA)
#pragma unroll
                    for (int qs = 0; qs < 2; qs++) {
                        int ql = wave * 32 + qs * 16 + l16;
#pragma unroll
                        for (int sb = 0; sb < 4; sb++)
#pragma unroll
                            for (int r = 0; r < 4; r++)
                                if (sb * 16 + quad * 4 + r > ql) SA[qs][sb][r] = -1e30f;
                    }
                }
#pragma unroll
                for (int qs = 0; qs < 2; qs++)
#pragma unroll
                    for (int sb = 0; sb < 4; sb++) {
#pragma unroll
                        for (int r = 0; r < 4; r++) SA[qs][sb][r] = exp2_fast(SA[qs][sb][r]);
                        union { unsigned u[2]; short4v v; } pk;
                        pk.u[0] = cvtpk(SA[qs][sb][0], SA[qs][sb][1]);
                        pk.u[1] = cvtpk(SA[qs][sb][2], SA[qs][sb][3]);
                        pfA[qs][sb] = pk.v;
                    }
            }
            // --- tile B through pfB (diagonal of qtB = 31-p >= 16 > limB:
            //     never reached in this sub-block -> no mask) ---
            if (doB) {
                floatx4 SB[2][4];
                __builtin_amdgcn_s_setprio(1);
#pragma unroll
                for (int sb = 0; sb < 4; sb++) {
                    short8 kf0 = *(const short8*)(ks + (sb * 16 + l16) * 72 + quad * 8);
                    short8 kf1 = *(const short8*)(ks + (sb * 16 + l16) * 72 + 32 + quad * 8);
#pragma unroll
                    for (int qs = 0; qs < 2; qs++) {
                        floatx4 t = zero;
                        t = __builtin_amdgcn_mfma_f32_16x16x32_bf16(kf0, qBf0[qs], t, 0, 0, 0);
                        t = __builtin_amdgcn_mfma_f32_16x16x32_bf16(kf1, qBf1[qs], t, 0, 0, 0);
                        SB[qs][sb] = t;
                    }
                }
                __builtin_amdgcn_s_setprio(0);
#pragma unroll
                for (int qs = 0; qs < 2; qs++)
#pragma unroll
                    for (int sb = 0; sb < 4; sb++) {
#pragma unroll
                        for (int r = 0; r < 4; r++) SB[qs][sb][r] = exp2_fast(SB[qs][sb][r]);
                        union { unsigned u[2]; short4v v; } pk;
                        pk.u[0] = cvtpk(SB[qs][sb][0], SB[qs][sb][1]);
                        pk.u[1] = cvtpk(SB[qs][sb][2], SB[qs][sb][3]);
                        pfB[qs][sb] = pk.v;
                    }
            }

            __builtin_amdgcn_s_setprio(1);
            // l accumulation via ones-row MFMA
#pragma unroll
            for (int qs = 0; qs < 2; qs++) {
                if (doA) {
                    lA[qs] = mfma16(ones, pfA[qs][0], lA[qs]);
                    lA[qs] = mfma16(ones, pfA[qs][1], lA[qs]);
                    lA[qs] = mfma16(ones, pfA[qs][2], lA[qs]);
                    lA[qs] = mfma16(ones, pfA[qs][3], lA[qs]);
                }
                if (doB) {
                    lB[qs] = mfma16(ones, pfB[qs][0], lB[qs]);
                    lB[qs] = mfma16(ones, pfB[qs][1], lB[qs]);
                    lB[qs] = mfma16(ones, pfB[qs][2], lB[qs]);
                    lB[qs] = mfma16(ones, pfB[qs][3], lB[qs]);
                }
            }
            // PV: V-frags read ONCE, applied to both tiles' accumulators
#pragma unroll
            for (int jd = 0; jd < 4; jd++) {
                const ushort_t* vrow = vs + (jd * 16 + l16) * 72 + quad * 16;
                short8 vA8 = *(const short8*)(vrow);       // sb0 | sb1
                short8 vB8 = *(const short8*)(vrow + 8);   // sb2 | sb3
                short4v v0 = __builtin_shufflevector(vA8, vA8, 0, 1, 2, 3);
                short4v v1 = __builtin_shufflevector(vA8, vA8, 4, 5, 6, 7);
                short4v v2 = __builtin_shufflevector(vB8, vB8, 0, 1, 2, 3);
                short4v v3 = __builtin_shufflevector(vB8, vB8, 4, 5, 6, 7);
#pragma unroll
                for (int qs = 0; qs < 2; qs++) {
                    if (doA) {
                        OA[qs][jd] = mfma16(v0, pfA[qs][0], OA[qs][jd]);
                        OA[qs][jd] = mfma16(v1, pfA[qs][1], OA[qs][jd]);
                        OA[qs][jd] = mfma16(v2, pfA[qs][2], OA[qs][jd]);
                        OA[qs][jd] = mfma16(v3, pfA[qs][3], OA[qs][jd]);
                    }
                    if (doB) {
                        OB[qs][jd] = mfma16(v0, pfB[qs][0], OB[qs][jd]);
                        OB[qs][jd] = mfma16(v1, pfB[qs][1], OB[qs][jd]);
                        OB[qs][jd] = mfma16(v2, pfB[qs][2], OB[qs][jd]);
                        OB[qs][jd] = mfma16(v3, pfB[qs][3], OB[qs][jd]);
                    }
                }
            }
            __builtin_amdgcn_s_setprio(0);
        }

        // epilogue A: full causal key range seen -> final bf16
#pragma unroll
        for (int qs = 0; qs < 2; qs++) {
            float rl = 1.0f / lA[qs][0];
            int row = b * TSEQ + qtA * 64 + wave * 32 + qs * 16 + l16;
#pragma unroll
            for (int jd = 0; jd < 4; jd++) {
                int col = h * 64 + jd * 16 + quad * 4;
                ushort4 o;
                o.x = f2bf(OA[qs][jd][0] * rl);
                o.y = f2bf(OA[qs][jd][1] * rl);
                o.z = f2bf(OA[qs][jd][2] * rl);
                o.w = f2bf(OA[qs][jd][3] * rl);
                *(ushort4*)(outb + (size_t)row * DMODEL + col) = o;
            }
        }
        // epilogue B: fp32 partial A for q-tile 31-p
#pragma unroll
        for (int qs = 0; qs < 2; qs++) {
            int prow = (qtB - 16) * 64 + wave * 32 + qs * 16 + l16;
            size_t rbase = ((size_t)bh * 1024 + prow) * 64;
#pragma unroll
            for (int jd = 0; jd < 4; jd++)
                *(floatx4*)(PO_a + rbase + jd * 16 + quad * 4) = OB[qs][jd];
            if (quad == 0) Pl_a[(size_t)bh * 1024 + prow] = lB[qs][0];
        }
        return;
    }

    // ---- sub == 1: q-tile 31-p, keys 16-p..31-p -> fp32 partial B ----
    {
        int qt = 31 - p, k0 = 16 - p, cnt = 16;

        short8 qf0[2], qf1[2];
#pragma unroll
        for (int qs = 0; qs < 2; qs++) {
            int qrow = qt * 64 + wave * 32 + qs * 16 + l16;
            qf0[qs] = *(const short8*)(qh + (size_t)qrow * 64 + quad * 8);
            qf1[qs] = *(const short8*)(qh + (size_t)qrow * 64 + 32 + quad * 8);
        }

        floatx4 Oacc[2][4];
#pragma unroll
        for (int qs = 0; qs < 2; qs++)
#pragma unroll
            for (int j = 0; j < 4; j++) Oacc[qs][j] = zero;
        floatx4 lacc[2];
        lacc[0] = zero; lacc[1] = zero;

        {
            const ushort_t* kt0 = kh + (size_t)k0 * TILE_ELEMS;
            const ushort_t* vt0 = vh + (size_t)k0 * TILE_ELEMS;
#pragma unroll
            for (int c = 0; c < 5; c++) {
                int cc = wave + 2 * c;
                if (cc < 9) {
                    glds16(kt0 + cc * 512 + lo8, &Ks[0][cc * 512]);
                    glds16(vt0 + cc * 512 + lo8, &Vs[0][cc * 512]);
                }
            }
        }

        for (int step = 0; step < cnt; step++) {
            int cur = step & 1;
            __syncthreads();
            if (step + 1 < cnt) {
                const ushort_t* kt = kh + (size_t)(k0 + step + 1) * TILE_ELEMS;
                const ushort_t* vt = vh + (size_t)(k0 + step + 1) * TILE_ELEMS;
#pragma unroll
                for (int c = 0; c < 5; c++) {
                    int cc = wave + 2 * c;
                    if (cc < 9) {
                        glds16(kt + cc * 512 + lo8, &Ks[cur ^ 1][cc * 512]);
                        glds16(vt + cc * 512 + lo8, &Vs[cur ^ 1][cc * 512]);
                    }
                }
            }
            const ushort_t* ks = &Ks[cur][0];
            const ushort_t* vs = &Vs[cur][0];

            floatx4 S[2][4];
            __builtin_amdgcn_s_setprio(1);
#pragma unroll
            for (int sb = 0; sb < 4; sb++) {
                short8 kf0 = *(const short8*)(ks + (sb * 16 + l16) * 72 + quad * 8);
                short8 kf1 = *(const short8*)(ks + (sb * 16 + l16) * 72 + 32 + quad * 8);
#pragma unroll
                for (int qs = 0; qs < 2; qs++) {
                    floatx4 t = zero;
                    t = __builtin_amdgcn_mfma_f32_16x16x32_bf16(kf0, qf0[qs], t, 0, 0, 0);
                    t = __builtin_amdgcn_mfma_f32_16x16x32_bf16(kf1, qf1[qs], t, 0, 0, 0);
                    S[qs][sb] = t;
                }
            }
            __builtin_amdgcn_s_setprio(0);
            if (k0 + step == qt) {   // diagonal (step == 15)
#pragma unroll
                for (int qs = 0; qs < 2; qs++) {
                    int ql = wave * 32 + qs * 16 + l16;
#pragma unroll
                    for (int sb = 0; sb < 4; sb++)
#pragma unroll
                        for (int r = 0; r < 4; r++)
                            if (sb * 16 + quad * 4 + r > ql) S[qs][sb][r] = -1e30f;
                }
            }
#pragma unroll
            for (int qs = 0; qs < 2; qs++)
#pragma unroll
                for (int sb = 0; sb < 4; sb++)
#pragma unroll
                    for (int r = 0; r < 4; r++)
                        S[qs][sb][r] = exp2_fast(S[qs][sb][r]);

            short4v pf[2][4];
#pragma unroll
            for (int qs = 0; qs < 2; qs++)
#pragma unroll
                for (int sb = 0; sb < 4; sb++) {
                    union { unsigned u[2]; short4v v; } pk;
                    pk.u[0] = cvtpk(S[qs][sb][0], S[qs][sb][1]);
                    pk.u[1] = cvtpk(S[qs][sb][2], S[qs][sb][3]);
                    pf[qs][sb] = pk.v;
                }
            __builtin_amdgcn_s_setprio(1);
#pragma unroll
            for (int qs = 0; qs < 2; qs++) {
                lacc[qs] = mfma16(ones, pf[qs][0], lacc[qs]);
                lacc[qs] = mfma16(ones, pf[qs][1], lacc[qs]);
                lacc[qs] = mfma16(ones, pf[qs][2], lacc[qs]);
                lacc[qs] = mfma16(ones, pf[qs][3], lacc[qs]);
            }
#pragma unroll
            for (int jd = 0; jd < 4; jd++) {
                const ushort_t* vrow = vs + (jd * 16 + l16) * 72 + quad * 16;
                short8 vA8 = *(const short8*)(vrow);
                short8 vB8 = *(const short8*)(vrow + 8);
                short4v v0 = __builtin_shufflevector(vA8, vA8, 0, 1, 2, 3);
                short4v v1 = __builtin_shufflevector(vA8, vA8, 4, 5, 6, 7);
                short4v v2 = __builtin_shufflevector(vB8, vB8, 0, 1, 2, 3);
                short4v v3 = __builtin_shufflevector(vB8, vB8, 4, 5, 6, 7);
#pragma unroll
                for (int qs = 0; qs < 2; qs++) {
                    Oacc[qs][jd] = mfma16(v0, pf[qs][0], Oacc[qs][jd]);
                    Oacc[qs][jd] = mfma16(v1, pf[qs][1], Oacc[qs][jd]);
                    Oacc[qs][jd] = mfma16(v2, pf[qs][2], Oacc[qs][jd]);
                    Oacc[qs][jd] = mfma16(v3, pf[qs][3], Oacc[qs][jd]);
                }
            }
            __builtin_amdgcn_s_setprio(0);
        }

#pragma unroll
        for (int qs = 0; qs < 2; qs++) {
            int prow = (qt - 16) * 64 + wave * 32 + qs * 16 + l16;
            size_t rbase = ((size_t)bh * 1024 + prow) * 64;
#pragma unroll
            for (int jd = 0; jd < 4; jd++)
                *(floatx4*)(PO_b + rbase + jd * 16 + quad * 4) = Oacc[qs][jd];
            if (quad == 0) Pl_b[(size_t)bh * 1024 + prow] = lacc[qs][0];
        }
    }
}

// combine upper-half rows: out = (O_A + O_B) / (l_A + l_B) -> bf16
__global__ void attn_combine(const float* __restrict__ PO_a,
                             const float* __restrict__ PO_b,
                             const float* __restrict__ Pl_a,
                             const float* __restrict__ Pl_b,
                             ushort_t* __restrict__ outb) {
    int i = blockIdx.x * 256 + threadIdx.x;
    int row = i >> 4;             // bh*1024 + prow
    int c4 = (i & 15) * 4;        // col within head
    float rl = 1.0f / (Pl_a[row] + Pl_b[row]);
    floatx4 a = *(const floatx4*)(PO_a + (size_t)row * 64 + c4);
    floatx4 c = *(const floatx4*)(PO_b + (size_t)row * 64 + c4);
    int bh = row >> 10, prow = row & 1023;
    int b = bh >> 4, h = bh & 15;
    int orow = b * TSEQ + 1024 + prow;
    ushort4 o;
    o.x = f2bf((a[0] + c[0]) * rl);
    o.y = f2bf((a[1] + c[1]) * rl);
    o.z = f2bf((a[2] + c[2]) * rl);
    o.w = f2bf((a[3] + c[3]) * rl);
    *(ushort4*)(outb + (size_t)orow * DMODEL + h * 64 + c4) = o;
}

// ---------------- fallback: paired attention ----------
__global__ __launch_bounds__(256, 1)
void attn_paired(const ushort_t* __restrict__ Qb,
                 const ushort_t* __restrict__ Kt,
                 const ushort_t* __restrict__ Vt,
                 ushort_t* __restrict__ outb) {
    __shared__ ushort_t Ks[2][64 * 72];
    __shared__ ushort_t Vs[2][64 * 72];
    int tid = threadIdx.x;
    int wave = tid >> 6, lane = tid & 63;
    int quad = lane >> 4, l16 = lane & 15;
    int pair = blockIdx.x;   // 0..15
    int bh = blockIdx.y;     // 0..31
    int b = bh >> 4, h = bh & 15;
    const ushort_t* qh = Qb + (size_t)bh * TSEQ * 64;
    const ushort_t* kh = Kt + (size_t)bh * BH_TILE_STRIDE;
    const ushort_t* vh = Vt + (size_t)bh * BH_TILE_STRIDE;
    const floatx4 zero = {0.f, 0.f, 0.f, 0.f};
    int lo8 = lane * 8;

    for (int half = 0; half < 2; half++) {
        int qt = half ? (31 - pair) : pair;
        int q0 = qt * 64;
        int nsteps = qt + 1;

        int qrow = q0 + wave * 16 + l16;
        short8 qf0 = *(const short8*)(qh + (size_t)qrow * 64 + quad * 8);
        short8 qf1 = *(const short8*)(qh + (size_t)qrow * 64 + 32 + quad * 8);

        floatx4 Oacc[4];
#pragma unroll
        for (int j = 0; j < 4; j++) Oacc[j] = zero;
        float lsum = 0.f;

#pragma unroll
        for (int c = 0; c < 3; c++) {
            int cc = wave + 4 * c;
            if (cc < 9) {
                glds16(kh + cc * 512 + lo8, &Ks[0][cc * 512]);
                glds16(vh + cc * 512 + lo8, &Vs[0][cc * 512]);
            }
        }

        for (int step = 0; step < nsteps; step++) {
            int cur = step & 1;
            __syncthreads();
            if (step + 1 < nsteps) {
                const ushort_t* kt = kh + (size_t)(step + 1) * TILE_ELEMS;
                const ushort_t* vt = vh + (size_t)(step + 1) * TILE_ELEMS;
#pragma unroll
                for (int c = 0; c < 3; c++) {
                    int cc = wave + 4 * c;
                    if (cc < 9) {
                        glds16(kt + cc * 512 + lo8, &Ks[cur ^ 1][cc * 512]);
                        glds16(vt + cc * 512 + lo8, &Vs[cur ^ 1][cc * 512]);
                    }
                }
            }
            const ushort_t* ks = &Ks[cur][0];
            const ushort_t* vs = &Vs[cur][0];

            floatx4 S[4];
#pragma unroll
            for (int sb = 0; sb < 4; sb++) {
                short8 kf0 = *(const short8*)(ks + (sb * 16 + l16) * 72 + quad * 8);
                short8 kf1 = *(const short8*)(ks + (sb * 16 + l16) * 72 + 32 + quad * 8);
                floatx4 s = zero;
                s = __builtin_amdgcn_mfma_f32_16x16x32_bf16(kf0, qf0, s, 0, 0, 0);
                s = __builtin_amdgcn_mfma_f32_16x16x32_bf16(kf1, qf1, s, 0, 0, 0);
                S[sb] = s;
            }
            if (step == nsteps - 1) {
                int ql = wave * 16 + l16;
#pragma unroll
                for (int sb = 0; sb < 4; sb++)
#pragma unroll
                    for (int r = 0; r < 4; r++)
                        if (sb * 16 + quad * 4 + r > ql) S[sb][r] = -1e30f;
            }
            float sum = 0.f;
#pragma unroll
            for (int sb = 0; sb < 4; sb++)
#pragma unroll
                for (int r = 0; r < 4; r++) {
                    float p = exp2_fast(S[sb][r]);
                    S[sb][r] = p;
                    sum += p;
                }
            lsum += sum;

            short4v pf[4];
#pragma unroll
            for (int sb = 0; sb < 4; sb++) {
                union { unsigned u[2]; short4v v; } pk;
                pk.u[0] = pk2bf(S[sb][0], S[sb][1]);
                pk.u[1] = pk2bf(S[sb][2], S[sb][3]);
                pf[sb] = pk.v;
            }
#pragma unroll
            for (int jd = 0; jd < 4; jd++) {
                const ushort_t* vrow = vs + (jd * 16 + l16) * 72 + quad * 16;
                short8 vA = *(const short8*)(vrow);
                short8 vB = *(const short8*)(vrow + 8);
                short4v v0 = __builtin_shufflevector(vA, vA, 0, 1, 2, 3);
                short4v v1 = __builtin_shufflevector(vA, vA, 4, 5, 6, 7);
                short4v v2 = __builtin_shufflevector(vB, vB, 0, 1, 2, 3);
                short4v v3 = __builtin_shufflevector(vB, vB, 4, 5, 6, 7);
                Oacc[jd] = mfma16(v0, pf[0], Oacc[jd]);
                Oacc[jd] = mfma16(v1, pf[1], Oacc[jd]);
                Oacc[jd] = mfma16(v2, pf[2], Oacc[jd]);
                Oacc[jd] = mfma16(v3, pf[3], Oacc[jd]);
            }
        }
        {
            float l = lsum;
            l += __shfl_xor(l, 16);
            l += __shfl_xor(l, 32);
            float rl = 1.0f / l;
            int row = b * TSEQ + q0 + wave * 16 + l16;
#pragma unroll
            for (int jd = 0; jd < 4; jd++) {
                int col = h * 64 + jd * 16 + quad * 4;
                ushort4 o;
                o.x = f2bf(Oacc[jd][0] * rl);
                o.y = f2bf(Oacc[jd][1] * rl);
                o.z = f2bf(Oacc[jd][2] * rl);
                o.w = f2bf(Oacc[jd][3] * rl);
                *(ushort4*)(outb + (size_t)row * DMODEL + col) = o;
            }
        }
        __syncthreads();
    }
}

extern "C" void kernel_launch(void* const* d_in, const int* in_sizes, int n_in,
                              void* d_out, int out_size, void* d_ws, size_t ws_size,
                              hipStream_t stream) {
    const float* x      = (const float*)d_in[0];
    const float* w_qkv  = (const float*)d_in[1];
    const float* b_qkv  = (const float*)d_in[2];
    const float* w_proj = (const float*)d_in[3];
    const float* b_proj = (const float*)d_in[4];
    float* out = (float*)d_out;
    char* ws = (char*)d_ws;

    // workspace (main path, ~64.3 MB):
    //  [0,8M):         xb (x bf16)
    //  [8M,14M):       wqkvT            -> dead after QKV; wprojT at 10M
    //  [14680064,+8M): Qb   [bh][2048][64]
    //  [23068672,+9M): Kt   [bh][32][64][72] tiled
    //  [32505856,+8M): attnb (attn output rows)
    //  [40894464,+9M): Vt   [bh][32][64][72] tiled-permuted (GEMM-direct)
    //  [50331648,+8M): PO_a fp32 partial O
    //  [58720256,+8M): PO_b fp32 partial O
    //  [67108864,128K): Pl_a; [67239936,128K): Pl_b
    ushort_t* xb     = (ushort_t*)(ws);
    ushort_t* wqkvT  = (ushort_t*)(ws + 8388608);
    ushort_t* wprojT = (ushort_t*)(ws + 10485760);
    ushort_t* Qb     = (ushort_t*)(ws + 14680064);
    ushort_t* Kt     = (ushort_t*)(ws + 23068672);
    ushort_t* attnb  = (ushort_t*)(ws + 32505856);
    ushort_t* Vt     = (ushort_t*)(ws + 40894464);
    float* PO_a = (float*)(ws + 50331648);
    float* PO_b = (float*)(ws + 58720256);
    float* Pl_a = (float*)(ws + 67108864);
    float* Pl_b = (float*)(ws + 67239936);
    const size_t ws_need = 67371008;

    cast_f32_bf16<<<4096, 256, 0, stream>>>(x, xb, MROWS * DMODEL);
    transpose_cast<<<dim3(NQKV / 32, DMODEL / 32), 256, 0, stream>>>(w_qkv, wqkvT, DMODEL, NQKV);

    if (ws_size >= ws_need) {
        // QKV: V written tiled-permuted directly (no transpose_v pass).
        gemm_glds<1, 4, 4><<<768, 256, 0, stream>>>(
            xb, wqkvT, b_qkv, Qb, Kt, Vt, MROWS, NQKV, DMODEL);
        transpose_cast<<<dim3(DMODEL / 32, DMODEL / 32), 256, 0, stream>>>(w_proj, wprojT, DMODEL, DMODEL);
        attn_split<<<dim3(1024), 128, 0, stream>>>(Qb, Kt, Vt, attnb,
                                                   PO_a, PO_b, Pl_a, Pl_b);
        attn_combine<<<dim3(2048), 256, 0, stream>>>(PO_a, PO_b, Pl_a, Pl_b, attnb);
    } else {
        // fallback (small ws): V linear + transpose_v + paired attention.
        ushort_t* Vb    = (ushort_t*)(ws + 32505856);
        ushort_t* VtOld = (ushort_t*)(ws);
        gemm_glds<2, 4, 4><<<768, 256, 0, stream>>>(
            xb, wqkvT, b_qkv, Qb, Kt, Vb, MROWS, NQKV, DMODEL);
        transpose_v<<<dim3(32, 32), 256, 0, stream>>>(Vb, VtOld);
        transpose_cast<<<dim3(DMODEL / 32, DMODEL / 32), 256, 0, stream>>>(w_proj, wprojT, DMODEL, DMODEL);
        attn_paired<<<dim3(16, 32), 256, 0, stream>>>(Qb, Kt, VtOld, Vb);
        // attn_paired wrote attnb == Vb region
        gemm_glds<0, 2, 8><<<512, 256, 0, stream>>>(
            Vb, wprojT, b_proj, out, nullptr, nullptr, MROWS, DMODEL, DMODEL);
        return;
    }

    // proj: 64 m-tiles (MFRAG=2) -> PERXCD=8; 8 n-tiles; 512 blocks 1-D.
    gemm_glds<0, 2, 8><<<512, 256, 0, stream>>>(
        attnb, wprojT, b_proj, out, nullptr, nullptr, MROWS, DMODEL, DMODEL);
}

// Round 10
// 180.939 us; speedup vs baseline: 1.0214x; 1.0214x over previous
//
#include <hip/hip_runtime.h>
#include <hip/hip_bf16.h>
#include <stdint.h>

// Problem constants: x[2,2048,1024], H=16, Dh=64
#define MROWS 4096   // B*T
#define DMODEL 1024
#define NQKV 3072
#define TSEQ 2048

typedef __attribute__((ext_vector_type(8))) short short8;   // 8 bf16 = 4 VGPRs
typedef __attribute__((ext_vector_type(4))) short short4v;  // 4 bf16 = 2 VGPRs
typedef __attribute__((ext_vector_type(4))) float floatx4;  // MFMA C/D
typedef unsigned short ushort_t;

// K/V tiled layouts for glds staging: [bh][32 tiles][64 rows][72] bf16.
#define TILE_ELEMS 4608        // 64*72
#define BH_TILE_STRIDE 147456  // 32*4608

// Q pre-scale: (1/sqrt(64)) * log2(e) -- attention softmax runs in base 2.
#define QSCALE 0.1803368801111204f

static __device__ __forceinline__ unsigned short f2bf(float f) {
    union { float f; unsigned u; } v; v.f = f;
    unsigned r = v.u + 0x7fff + ((v.u >> 16) & 1);   // RNE
    return (unsigned short)(r >> 16);
}

// --- target-specific intrinsic wrappers -------------------------------------
// hipcc compiles this TU twice (device gfx950 + host x86). Host pass must
// PARSE device code but never executes it; gate amdgcn-only builtins on
// __HIP_DEVICE_COMPILE__ so the host pass gets plain-C fallbacks.

// D = A*B + C, 16x16x16 bf16 (A,B: 4 bf16/lane; C/D: 4 fp32/lane)
static __device__ __forceinline__ floatx4 mfma16(short4v a, short4v b, floatx4 c) {
#if defined(__HIP_DEVICE_COMPILE__)
#if __has_builtin(__builtin_amdgcn_mfma_f32_16x16x16bf16_1k)
    return __builtin_amdgcn_mfma_f32_16x16x16bf16_1k(a, b, c, 0, 0, 0);
#else
#error "mfma 16x16x16 bf16 builtin unavailable on device"
#endif
#else
    return c;   // host pass: parse-only, never executed
#endif
}

// pack two fp32 -> two bf16 (round-half-up): low16 = bf16(a), high16 = bf16(b).
static __device__ __forceinline__ unsigned pk2bf(float a, float b) {
    unsigned ua = __float_as_uint(a) + 0x8000u;
    unsigned ub = __float_as_uint(b) + 0x8000u;
#if defined(__HIP_DEVICE_COMPILE__) && __has_builtin(__builtin_amdgcn_perm)
    return __builtin_amdgcn_perm(ub, ua, 0x07060302u);  // {ub.b3,ub.b2,ua.b3,ua.b2}
#else
    return (ua >> 16) | (ub & 0xFFFF0000u);
#endif
}

// pack two fp32 -> two bf16 via the HW packed converter (RNE), 1 instr vs 3.
static __device__ __forceinline__ unsigned cvtpk(float a, float b) {
#if defined(__HIP_DEVICE_COMPILE__)
    unsigned r;
    asm("v_cvt_pk_bf16_f32 %0, %1, %2" : "=v"(r) : "v"(a), "v"(b));
    return r;
#else
    return pk2bf(a, b);   // host pass: parse-only
#endif
}

static __device__ __forceinline__ float exp2_fast(float x) {
#if defined(__HIP_DEVICE_COMPILE__) && __has_builtin(__builtin_amdgcn_exp2f)
    return __builtin_amdgcn_exp2f(x);
#else
    return exp2f(x);
#endif
}

// async global->LDS, 16B per lane. Global addr must be PER-LANE; LDS dest is
// wave-uniform base + lane*16.
static __device__ __forceinline__ void glds16(const void* g, void* l) {
    __builtin_amdgcn_global_load_lds(
        (const __attribute__((address_space(1))) void*)g,
        (__attribute__((address_space(3))) void*)l, 16, 0, 0);
}

// ---------------- cast fp32 -> bf16 (n multiple of 4) ----------------
__global__ void cast_f32_bf16(const float* __restrict__ in,
                              ushort_t* __restrict__ out, int n) {
    int i = (blockIdx.x * blockDim.x + threadIdx.x) * 4;
    if (i < n) {
        float4 f = *(const float4*)(in + i);
        ushort4 o;
        o.x = f2bf(f.x); o.y = f2bf(f.y); o.z = f2bf(f.z); o.w = f2bf(f.w);
        *(ushort4*)(out + i) = o;
    }
}

// ---------------- transpose + cast: in[R][C] f32 -> out[C][R] bf16 ----------------
__global__ void transpose_cast(const float* __restrict__ in,
                               ushort_t* __restrict__ out, int R, int C) {
    __shared__ float tile[32][33];
    int c0 = blockIdx.x * 32, r0 = blockIdx.y * 32;
    int tx = threadIdx.x & 31, ty = threadIdx.x >> 5;
    for (int i = 0; i < 4; i++) {
        int r = ty + i * 8;
        tile[r][tx] = in[(size_t)(r0 + r) * C + c0 + tx];
    }
    __syncthreads();
    for (int i = 0; i < 4; i++) {
        int r = ty + i * 8;
        out[(size_t)(c0 + r) * R + r0 + tx] = f2bf(tile[tx][r]);
    }
}

// ---------------- V transpose (FALLBACK PATH ONLY): Vb -> Vt tiled ----------
__global__ void transpose_v(const ushort_t* __restrict__ in,
                            ushort_t* __restrict__ out) {
    __shared__ ushort_t T[64][72];
    int tile = blockIdx.x, bh = blockIdx.y;
    int tid = threadIdx.x;
    int row = tid >> 2, q4 = tid & 3;
    const ushort_t* ip = in + ((size_t)bh * TSEQ + tile * 64) * 64;
#pragma unroll
    for (int p = 0; p < 2; p++) {
        int c = q4 * 16 + p * 8;
        *(uint4*)(&T[row][c]) = *(const uint4*)(ip + (size_t)row * 64 + c);
    }
    __syncthreads();
    ushort_t* op = out + (size_t)bh * BH_TILE_STRIDE + (size_t)tile * TILE_ELEMS;
#pragma unroll
    for (int p = 0; p < 2; p++) {
        int cbase = q4 * 16 + p * 8;          // c' chunk base
        ushort_t tmp[8];
#pragma unroll
        for (int e = 0; e < 8; e++) {
            int cp = cbase + e;               // c' = 16*Q + 4*SB + J
            int Q = cp >> 4, SB = (cp >> 2) & 3, J = cp & 3;
            int s = SB * 16 + Q * 4 + J;
            tmp[e] = T[s][row];               // row = d
        }
        *(uint4*)(op + (size_t)row * 72 + cbase) = *(uint4*)tmp;
    }
}

// ---------------- GEMM (dbuf 2-phase, BK=32), XCD-swizzled 1-D grid ----------
// C = A[M][K] @ Bt[N][K]^T + bias.  (round-6 proven version, 180.7 us x2)
// T3-minimum recipe: double-buffered LDS, prefetch of tile k+32 ISSUED BEFORE
// the ds_read+MFMA of tile k, single __syncthreads per K-step. Round-8 showed
// deeper pipelining (3-buffer counted vmcnt) REGRESSES (extra LDS cuts proj
// occupancy); round-7 showed swizzle regresses. This is the structural floor
// for the 128-tile shape at these problem dims.
// Block mapping: id -> xcd = id&7, each XCD owns PERXCD consecutive m-tiles.
// EPI 0: fp32 out0[M][N] + bias.
// EPI 1: Q -> [bh][t][64] bf16 *QSCALE; K -> tiled; V -> tiled-permuted direct.
// EPI 2: like EPI 1 but V linear (fallback, feeds transpose_v).
template <int EPI, int MFRAG, int PERXCD>
__global__ __launch_bounds__(256, 3)
void gemm_glds(const ushort_t* __restrict__ A,
               const ushort_t* __restrict__ Bt,
               const float* __restrict__ bias,
               void* __restrict__ out0, void* __restrict__ out1, void* __restrict__ out2,
               int M, int N, int K) {
    __shared__ ushort_t As[2][MFRAG * 32 * 32];
    __shared__ ushort_t Bs[2][128 * 32];
    int tid = threadIdx.x;
    int wave = tid >> 6, lane = tid & 63;
    int quad = lane >> 4, l16 = lane & 15;
    // XCD swizzle (PERXCD is a power of two)
    int id = blockIdx.x;
    int xcd = id & 7, sidx = id >> 3;
    int m_idx = xcd * PERXCD + (sidx & (PERXCD - 1));
    int n_idx = sidx / PERXCD;
    int m0 = m_idx * (MFRAG * 32), n0 = n_idx * 128;
    int wm = (wave & 1) * (MFRAG * 16), wn = (wave >> 1) * 64;

    const floatx4 zero = {0.f, 0.f, 0.f, 0.f};
    floatx4 acc[MFRAG][4];
#pragma unroll
    for (int i = 0; i < MFRAG; i++)
#pragma unroll
        for (int j = 0; j < 4; j++) acc[i][j] = zero;

    int srow = tid >> 2, sc = tid & 3;
    const ushort_t* ag = A  + (size_t)(m0 + srow) * K + sc * 8;
    const ushort_t* bg = Bt + (size_t)(n0 + srow) * K + sc * 8;
    int woff = wave * 512;

    // prologue: stage tile 0 into buffer 0, drain, then loop with prefetch
    glds16(ag, &As[0][woff]);
    if (MFRAG == 4) glds16(ag + (size_t)64 * K, &As[0][woff + 2048]);
    glds16(bg, &Bs[0][woff]);
    glds16(bg + (size_t)64 * K, &Bs[0][woff + 2048]);
    __syncthreads();

    int cur = 0;
    for (int k0 = 0; k0 < K; k0 += 32) {
        if (k0 + 32 < K) {
            int nb = cur ^ 1, kn = k0 + 32;
            glds16(ag + kn, &As[nb][woff]);
            if (MFRAG == 4) glds16(ag + (size_t)64 * K + kn, &As[nb][woff + 2048]);
            glds16(bg + kn, &Bs[nb][woff]);
            glds16(bg + (size_t)64 * K + kn, &Bs[nb][woff + 2048]);
        }
        short8 af[MFRAG], bf[4];
#pragma unroll
        for (int i = 0; i < MFRAG; i++)
            af[i] = *(const short8*)(&As[cur][(wm + i * 16 + l16) * 32 + quad * 8]);
#pragma unroll
        for (int j = 0; j < 4; j++)
            bf[j] = *(const short8*)(&Bs[cur][(wn + j * 16 + l16) * 32 + quad * 8]);
#pragma unroll
        for (int i = 0; i < MFRAG; i++)
#pragma unroll
            for (int j = 0; j < 4; j++)
                acc[i][j] = __builtin_amdgcn_mfma_f32_16x16x32_bf16(
                    af[i], bf[j], acc[i][j], 0, 0, 0);
        __syncthreads();   // emits vmcnt(0) lgkmcnt(0): prefetch has had
        cur ^= 1;          // the whole MFMA block to land
    }

    int sec = n0 >> 10;   // block-uniform (EPI!=0): 0=Q, 1=K, 2=V
    ushort_t* dst = (ushort_t*)(sec == 0 ? out0 : (sec == 1 ? out1 : out2));

    if (EPI == 1 && sec == 2) {
        // V -> tiled-permuted Vt, one 8B store per fragment
#pragma unroll
        for (int i = 0; i < MFRAG; i++) {
            int row = m0 + wm + i * 16 + quad * 4;
            int Abits = ((wm >> 4) + i) & 3;        // SB of s = t_local
            int b = row >> 11, t = row & 2047;
            int tile = t >> 6;
            int colp = 16 * quad + 4 * Abits;       // col' base; r adds 0..3
#pragma unroll
            for (int j = 0; j < 4; j++) {
                int col = n0 + wn + j * 16 + l16;
                int within = col & 1023, h = within >> 6, d = within & 63;
                size_t bh = (size_t)(b * 16 + h);
                float bvs = bias[col];
                ushort4 o;
                o.x = f2bf(acc[i][j][0] + bvs);
                o.y = f2bf(acc[i][j][1] + bvs);
                o.z = f2bf(acc[i][j][2] + bvs);
                o.w = f2bf(acc[i][j][3] + bvs);
                *(ushort4*)(dst + bh * BH_TILE_STRIDE + (size_t)tile * TILE_ELEMS
                            + (size_t)d * 72 + colp) = o;
            }
        }
        return;
    }

#pragma unroll
    for (int i = 0; i < MFRAG; i++) {
        int row = m0 + wm + i * 16 + quad * 4;
#pragma unroll
        for (int j = 0; j < 4; j++) {
            int col = n0 + wn + j * 16 + l16;
            float bvs = bias[col];
#pragma unroll
            for (int r = 0; r < 4; r++) {
                float v = acc[i][j][r] + bvs;
                int rowr = row + r;
                if (EPI == 0) {
                    ((float*)out0)[(size_t)rowr * N + col] = v;
                } else {
                    int b = rowr >> 11, t = rowr & 2047;
                    int within = col & 1023, h = within >> 6, d = within & 63;
                    size_t bh = (size_t)(b * 16 + h);
                    if (sec == 0)
                        dst[(bh * 2048 + t) * 64 + d] = f2bf(v * QSCALE);
                    else if (sec == 1)
                        dst[bh * BH_TILE_STRIDE + (size_t)(t >> 6) * TILE_ELEMS
                            + (size_t)(t & 63) * 72 + d] = f2bf(v);
                    else
                        dst[(bh * 2048 + t) * 64 + d] = f2bf(v);   // EPI==2 linear V
                }
            }
        }
    }
}

// ---------------- flash attention, key-split uniform blocks, 2-wave ----------
// Round-6 proven version (180.7 us x2). 2 waves x 32 q-rows; each K/V LDS
// fragment read once per wave, reused for two q-slices. Round-9's merged
// key-stream variant REGRESSED (+4 us: dual q-tile state ~ +96 VGPR ->
// occupancy/spill) -- reverted.
// Q: [bh][t][64] (pre-scaled by QSCALE). Kt/Vt: [bh][32][64][72] tiled
// (Vt column-permuted). out: [b*2048+t][h*64+d] bf16.
// Base-2 softmax, no max-shift: partials merge by addition -> key-split:
//   sub0 (17 steps): q-tile p keys 0..p -> final bf16; + q-tile 31-p keys
//   0..15-p -> fp32 partial A.  sub1 (16 steps): keys 16-p..31-p -> partial B.
// attn_combine does (O_A+O_B)/(l_A+l_B) for the upper 1024 rows.
// XCD-affine: id&7 -> XCD, 4 bh per XCD (K/V L2-resident; FETCH 139->13 MB).
__global__ __launch_bounds__(128, 2)
void attn_split(const ushort_t* __restrict__ Qb,
                const ushort_t* __restrict__ Kt,
                const ushort_t* __restrict__ Vt,
                ushort_t* __restrict__ outb,
                float* __restrict__ PO_a, float* __restrict__ PO_b,
                float* __restrict__ Pl_a, float* __restrict__ Pl_b) {
    __shared__ ushort_t Ks[2][64 * 72];
    __shared__ ushort_t Vs[2][64 * 72];
    int tid = threadIdx.x;
    int wave = tid >> 6, lane = tid & 63;   // wave 0..1
    int quad = lane >> 4, l16 = lane & 15;
    int id = blockIdx.x;                  // 0..1023
    int g = id >> 3;                      // 0..127
    int bh = (id & 7) * 4 + (g >> 5);     // XCD-affine: id&7 -> XCD, 4 bh/XCD
    int rem = g & 31;
    int p = rem >> 1, sub = rem & 1;      // pair 0..15, sub-block 0/1
    int b = bh >> 4, h = bh & 15;
    const ushort_t* qh = Qb + (size_t)bh * TSEQ * 64;
    const ushort_t* kh = Kt + (size_t)bh * BH_TILE_STRIDE;
    const ushort_t* vh = Vt + (size_t)bh * BH_TILE_STRIDE;
    const floatx4 zero = {0.f, 0.f, 0.f, 0.f};
    const short4v ones = {(short)0x3F80, (short)0x3F80, (short)0x3F80, (short)0x3F80};
    int lo8 = lane * 8;   // per-lane 16B offset for glds global addresses

    int nseg = sub ? 1 : 2;
    for (int seg = 0; seg < nseg; seg++) {
        int qt, k0, cnt, mode;   // mode: 0=direct bf16, 1=partial A, 2=partial B
        if (sub)           { qt = 31 - p; k0 = 16 - p; cnt = 16;     mode = 2; }
        else if (seg == 0) { qt = p;      k0 = 0;      cnt = p + 1;  mode = 0; }
        else               { qt = 31 - p; k0 = 0;      cnt = 16 - p; mode = 1; }

        // Q fragments for the wave's TWO 16-row q-slices; B-operand (n=l16).
        short8 qf0[2], qf1[2];
#pragma unroll
        for (int qs = 0; qs < 2; qs++) {
            int qrow = qt * 64 + wave * 32 + qs * 16 + l16;
            qf0[qs] = *(const short8*)(qh + (size_t)qrow * 64 + quad * 8);
            qf1[qs] = *(const short8*)(qh + (size_t)qrow * 64 + 32 + quad * 8);
        }

        floatx4 Oacc[2][4];
#pragma unroll
        for (int qs = 0; qs < 2; qs++)
#pragma unroll
            for (int j = 0; j < 4; j++) Oacc[qs][j] = zero;
        floatx4 lacc[2];
        lacc[0] = zero; lacc[1] = zero;

        // all waves done reading previous segment's buffers before reuse
        __syncthreads();
        // preload tile k0 -> buffer 0 (9 KB each = 9 x 1KB glds, 2 waves)
        {
            const ushort_t* kt0 = kh + (size_t)k0 * TILE_ELEMS;
            const ushort_t* vt0 = vh + (size_t)k0 * TILE_ELEMS;
#pragma unroll
            for (int c = 0; c < 5; c++) {
                int cc = wave + 2 * c;
                if (cc < 9) {
                    glds16(kt0 + cc * 512 + lo8, &Ks[0][cc * 512]);
                    glds16(vt0 + cc * 512 + lo8, &Vs[0][cc * 512]);
                }
            }
        }

        for (int step = 0; step < cnt; step++) {
            int cur = step & 1;
            __syncthreads();
            if (step + 1 < cnt) {
                const ushort_t* kt = kh + (size_t)(k0 + step + 1) * TILE_ELEMS;
                const ushort_t* vt = vh + (size_t)(k0 + step + 1) * TILE_ELEMS;
#pragma unroll
                for (int c = 0; c < 5; c++) {
                    int cc = wave + 2 * c;
                    if (cc < 9) {
                        glds16(kt + cc * 512 + lo8, &Ks[cur ^ 1][cc * 512]);
                        glds16(vt + cc * 512 + lo8, &Vs[cur ^ 1][cc * 512]);
                    }
                }
            }
            const ushort_t* ks = &Ks[cur][0];
            const ushort_t* vs = &Vs[cur][0];

            // S^T = K Q^T : K-frag read ONCE per sb, used for both q-slices.
            floatx4 S[2][4];
            __builtin_amdgcn_s_setprio(1);
#pragma unroll
            for (int sb = 0; sb < 4; sb++) {
                short8 kf0 = *(const short8*)(ks + (sb * 16 + l16) * 72 + quad * 8);
                short8 kf1 = *(const short8*)(ks + (sb * 16 + l16) * 72 + 32 + quad * 8);
#pragma unroll
                for (int qs = 0; qs < 2; qs++) {
                    floatx4 s = zero;
                    s = __builtin_amdgcn_mfma_f32_16x16x32_bf16(kf0, qf0[qs], s, 0, 0, 0);
                    s = __builtin_amdgcn_mfma_f32_16x16x32_bf16(kf1, qf1[qs], s, 0, 0, 0);
                    S[qs][sb] = s;
                }
            }
            __builtin_amdgcn_s_setprio(0);
            // causal mask only on the true diagonal tile (k0+step == qt)
            if (k0 + step == qt) {
#pragma unroll
                for (int qs = 0; qs < 2; qs++) {
                    int ql = wave * 32 + qs * 16 + l16;
#pragma unroll
                    for (int sb = 0; sb < 4; sb++)
#pragma unroll
                        for (int r = 0; r < 4; r++)
                            if (sb * 16 + quad * 4 + r > ql) S[qs][sb][r] = -1e30f;
                }
            }
            // p = 2^s (log2e folded into Q scale); 2^(-1e30) == 0 for masked
#pragma unroll
            for (int qs = 0; qs < 2; qs++)
#pragma unroll
                for (int sb = 0; sb < 4; sb++)
#pragma unroll
                    for (int r = 0; r < 4; r++)
                        S[qs][sb][r] = exp2_fast(S[qs][sb][r]);

            // P^T B-frags via packed HW converter
            short4v pf[2][4];
#pragma unroll
            for (int qs = 0; qs < 2; qs++)
#pragma unroll
                for (int sb = 0; sb < 4; sb++) {
                    union { unsigned u[2]; short4v v; } pk;
                    pk.u[0] = cvtpk(S[qs][sb][0], S[qs][sb][1]);
                    pk.u[1] = cvtpk(S[qs][sb][2], S[qs][sb][3]);
                    pf[qs][sb] = pk.v;
                }
            __builtin_amdgcn_s_setprio(1);
            // l accumulation: ones-row MFMA, two independent chains
#pragma unroll
            for (int qs = 0; qs < 2; qs++) {
                lacc[qs] = mfma16(ones, pf[qs][0], lacc[qs]);
                lacc[qs] = mfma16(ones, pf[qs][1], lacc[qs]);
                lacc[qs] = mfma16(ones, pf[qs][2], lacc[qs]);
                lacc[qs] = mfma16(ones, pf[qs][3], lacc[qs]);
            }
            // O^T += V^T P^T : V-frag read ONCE per d-tile, used for both qs.
#pragma unroll
            for (int jd = 0; jd < 4; jd++) {
                const ushort_t* vrow = vs + (jd * 16 + l16) * 72 + quad * 16;
                short8 vA = *(const short8*)(vrow);       // sb0 | sb1
                short8 vB = *(const short8*)(vrow + 8);   // sb2 | sb3
                short4v v0 = __builtin_shufflevector(vA, vA, 0, 1, 2, 3);
                short4v v1 = __builtin_shufflevector(vA, vA, 4, 5, 6, 7);
                short4v v2 = __builtin_shufflevector(vB, vB, 0, 1, 2, 3);
                short4v v3 = __builtin_shufflevector(vB, vB, 4, 5, 6, 7);
#pragma unroll
                for (int qs = 0; qs < 2; qs++) {
                    Oacc[qs][jd] = mfma16(v0, pf[qs][0], Oacc[qs][jd]);
                    Oacc[qs][jd] = mfma16(v1, pf[qs][1], Oacc[qs][jd]);
                    Oacc[qs][jd] = mfma16(v2, pf[qs][2], Oacc[qs][jd]);
                    Oacc[qs][jd] = mfma16(v3, pf[qs][3], Oacc[qs][jd]);
                }
            }
            __builtin_amdgcn_s_setprio(0);
        }

        if (mode == 0) {
            // full row of keys seen: normalize and store final bf16
#pragma unroll
            for (int qs = 0; qs < 2; qs++) {
                float rl = 1.0f / lacc[qs][0];
                int row = b * TSEQ + qt * 64 + wave * 32 + qs * 16 + l16;
#pragma unroll
                for (int jd = 0; jd < 4; jd++) {
                    int col = h * 64 + jd * 16 + quad * 4;
                    ushort4 o;
                    o.x = f2bf(Oacc[qs][jd][0] * rl);
                    o.y = f2bf(Oacc[qs][jd][1] * rl);
                    o.z = f2bf(Oacc[qs][jd][2] * rl);
                    o.w = f2bf(Oacc[qs][jd][3] * rl);
                    *(ushort4*)(outb + (size_t)row * DMODEL + col) = o;
                }
            }
        } else {
            // fp32 partial: [bh][prow][64] O and [bh][prow] l (upper q-tiles only)
            float* PO = (mode == 1) ? PO_a : PO_b;
            float* Pl = (mode == 1) ? Pl_a : Pl_b;
#pragma unroll
            for (int qs = 0; qs < 2; qs++) {
                int prow = (qt - 16) * 64 + wave * 32 + qs * 16 + l16;
                size_t rbase = ((size_t)bh * 1024 + prow) * 64;
#pragma unroll
                for (int jd = 0; jd < 4; jd++)
                    *(floatx4*)(PO + rbase + jd * 16 + quad * 4) = Oacc[qs][jd];
                if (quad == 0) Pl[(size_t)bh * 1024 + prow] = lacc[qs][0];
            }
        }
    }
}

// combine upper-half rows: out = (O_A + O_B) / (l_A + l_B) -> bf16
__global__ void attn_combine(const float* __restrict__ PO_a,
                             const float* __restrict__ PO_b,
                             const float* __restrict__ Pl_a,
                             const float* __restrict__ Pl_b,
                             ushort_t* __restrict__ outb) {
    int i = blockIdx.x * 256 + threadIdx.x;
    int row = i >> 4;             // bh*1024 + prow
    int c4 = (i & 15) * 4;        // col within head
    float rl = 1.0f / (Pl_a[row] + Pl_b[row]);
    floatx4 a = *(const floatx4*)(PO_a + (size_t)row * 64 + c4);
    floatx4 c = *(const floatx4*)(PO_b + (size_t)row * 64 + c4);
    int bh = row >> 10, prow = row & 1023;
    int b = bh >> 4, h = bh & 15;
    int orow = b * TSEQ + 1024 + prow;
    ushort4 o;
    o.x = f2bf((a[0] + c[0]) * rl);
    o.y = f2bf((a[1] + c[1]) * rl);
    o.z = f2bf((a[2] + c[2]) * rl);
    o.w = f2bf((a[3] + c[3]) * rl);
    *(ushort4*)(outb + (size_t)orow * DMODEL + h * 64 + c4) = o;
}

// ---------------- fallback: paired attention ----------
__global__ __launch_bounds__(256, 1)
void attn_paired(const ushort_t* __restrict__ Qb,
                 const ushort_t* __restrict__ Kt,
                 const ushort_t* __restrict__ Vt,
                 ushort_t* __restrict__ outb) {
    __shared__ ushort_t Ks[2][64 * 72];
    __shared__ ushort_t Vs[2][64 * 72];
    int tid = threadIdx.x;
    int wave = tid >> 6, lane = tid & 63;
    int quad = lane >> 4, l16 = lane & 15;
    int pair = blockIdx.x;   // 0..15
    int bh = blockIdx.y;     // 0..31
    int b = bh >> 4, h = bh & 15;
    const ushort_t* qh = Qb + (size_t)bh * TSEQ * 64;
    const ushort_t* kh = Kt + (size_t)bh * BH_TILE_STRIDE;
    const ushort_t* vh = Vt + (size_t)bh * BH_TILE_STRIDE;
    const floatx4 zero = {0.f, 0.f, 0.f, 0.f};
    int lo8 = lane * 8;

    for (int half = 0; half < 2; half++) {
        int qt = half ? (31 - pair) : pair;
        int q0 = qt * 64;
        int nsteps = qt + 1;

        int qrow = q0 + wave * 16 + l16;
        short8 qf0 = *(const short8*)(qh + (size_t)qrow * 64 + quad * 8);
        short8 qf1 = *(const short8*)(qh + (size_t)qrow * 64 + 32 + quad * 8);

        floatx4 Oacc[4];
#pragma unroll
        for (int j = 0; j < 4; j++) Oacc[j] = zero;
        float lsum = 0.f;

#pragma unroll
        for (int c = 0; c < 3; c++) {
            int cc = wave + 4 * c;
            if (cc < 9) {
                glds16(kh + cc * 512 + lo8, &Ks[0][cc * 512]);
                glds16(vh + cc * 512 + lo8, &Vs[0][cc * 512]);
            }
        }

        for (int step = 0; step < nsteps; step++) {
            int cur = step & 1;
            __syncthreads();
            if (step + 1 < nsteps) {
                const ushort_t* kt = kh + (size_t)(step + 1) * TILE_ELEMS;
                const ushort_t* vt = vh + (size_t)(step + 1) * TILE_ELEMS;
#pragma unroll
                for (int c = 0; c < 3; c++) {
                    int cc = wave + 4 * c;
                    if (cc < 9) {
                        glds16(kt + cc * 512 + lo8, &Ks[cur ^ 1][cc * 512]);
                        glds16(vt + cc * 512 + lo8, &Vs[cur ^ 1][cc * 512]);
                    }
                }
            }
            const ushort_t* ks = &Ks[cur][0];
            const ushort_t* vs = &Vs[cur][0];

            floatx4 S[4];
#pragma unroll
            for (int sb = 0; sb < 4; sb++) {
                short8 kf0 = *(const short8*)(ks + (sb * 16 + l16) * 72 + quad * 8);
                short8 kf1 = *(const short8*)(ks + (sb * 16 + l16) * 72 + 32 + quad * 8);
                floatx4 s = zero;
                s = __builtin_amdgcn_mfma_f32_16x16x32_bf16(kf0, qf0, s, 0, 0, 0);
                s = __builtin_amdgcn_mfma_f32_16x16x32_bf16(kf1, qf1, s, 0, 0, 0);
                S[sb] = s;
            }
            if (step == nsteps - 1) {
                int ql = wave * 16 + l16;
#pragma unroll
                for (int sb = 0; sb < 4; sb++)
#pragma unroll
                    for (int r = 0; r < 4; r++)
                        if (sb * 16 + quad * 4 + r > ql) S[sb][r] = -1e30f;
            }
            float sum = 0.f;
#pragma unroll
            for (int sb = 0; sb < 4; sb++)
#pragma unroll
                for (int r = 0; r < 4; r++) {
                    float p = exp2_fast(S[sb][r]);
                    S[sb][r] = p;
                    sum += p;
                }
            lsum += sum;

            short4v pf[4];
#pragma unroll
            for (int sb = 0; sb < 4; sb++) {
                union { unsigned u[2]; short4v v; } pk;
                pk.u[0] = pk2bf(S[sb][0], S[sb][1]);
                pk.u[1] = pk2bf(S[sb][2], S[sb][3]);
                pf[sb] = pk.v;
            }
#pragma unroll
            for (int jd = 0; jd < 4; jd++) {
                const ushort_t* vrow = vs + (jd * 16 + l16) * 72 + quad * 16;
                short8 vA = *(const short8*)(vrow);
                short8 vB = *(const short8*)(vrow + 8);
                short4v v0 = __builtin_shufflevector(vA, vA, 0, 1, 2, 3);
                short4v v1 = __builtin_shufflevector(vA, vA, 4, 5, 6, 7);
                short4v v2 = __builtin_shufflevector(vB, vB, 0, 1, 2, 3);
                short4v v3 = __builtin_shufflevector(vB, vB, 4, 5, 6, 7);
                Oacc[jd] = mfma16(v0, pf[0], Oacc[jd]);
                Oacc[jd] = mfma16(v1, pf[1], Oacc[jd]);
                Oacc[jd] = mfma16(v2, pf[2], Oacc[jd]);
                Oacc[jd] = mfma16(v3, pf[3], Oacc[jd]);
            }
        }
        {
            float l = lsum;
            l += __shfl_xor(l, 16);
            l += __shfl_xor(l, 32);
            float rl = 1.0f / l;
            int row = b * TSEQ + q0 + wave * 16 + l16;
#pragma unroll
            for (int jd = 0; jd < 4; jd++) {
                int col = h * 64 + jd * 16 + quad * 4;
                ushort4 o;
                o.x = f2bf(Oacc[jd][0] * rl);
                o.y = f2bf(Oacc[jd][1] * rl);
                o.z = f2bf(Oacc[jd][2] * rl);
                o.w = f2bf(Oacc[jd][3] * rl);
                *(ushort4*)(outb + (size_t)row * DMODEL + col) = o;
            }
        }
        __syncthreads();
    }
}

extern "C" void kernel_launch(void* const* d_in, const int* in_sizes, int n_in,
                              void* d_out, int out_size, void* d_ws, size_t ws_size,
                              hipStream_t stream) {
    const float* x      = (const float*)d_in[0];
    const float* w_qkv  = (const float*)d_in[1];
    const float* b_qkv  = (const float*)d_in[2];
    const float* w_proj = (const float*)d_in[3];
    const float* b_proj = (const float*)d_in[4];
    float* out = (float*)d_out;
    char* ws = (char*)d_ws;

    // workspace (main path, ~64.3 MB):
    //  [0,8M):         xb (x bf16)
    //  [8M,14M):       wqkvT            -> dead after QKV; wprojT at 10M
    //  [14680064,+8M): Qb   [bh][2048][64]
    //  [23068672,+9M): Kt   [bh][32][64][72] tiled
    //  [32505856,+8M): attnb (attn output rows)
    //  [40894464,+9M): Vt   [bh][32][64][72] tiled-permuted (GEMM-direct)
    //  [50331648,+8M): PO_a fp32 partial O
    //  [58720256,+8M): PO_b fp32 partial O
    //  [67108864,128K): Pl_a; [67239936,128K): Pl_b
    ushort_t* xb     = (ushort_t*)(ws);
    ushort_t* wqkvT  = (ushort_t*)(ws + 8388608);
    ushort_t* wprojT = (ushort_t*)(ws + 10485760);
    ushort_t* Qb     = (ushort_t*)(ws + 14680064);
    ushort_t* Kt     = (ushort_t*)(ws + 23068672);
    ushort_t* attnb  = (ushort_t*)(ws + 32505856);
    ushort_t* Vt     = (ushort_t*)(ws + 40894464);
    float* PO_a = (float*)(ws + 50331648);
    float* PO_b = (float*)(ws + 58720256);
    float* Pl_a = (float*)(ws + 67108864);
    float* Pl_b = (float*)(ws + 67239936);
    const size_t ws_need = 67371008;

    cast_f32_bf16<<<4096, 256, 0, stream>>>(x, xb, MROWS * DMODEL);
    transpose_cast<<<dim3(NQKV / 32, DMODEL / 32), 256, 0, stream>>>(w_qkv, wqkvT, DMODEL, NQKV);

    if (ws_size >= ws_need) {
        // QKV: V written tiled-permuted directly (no transpose_v pass).
        gemm_glds<1, 4, 4><<<768, 256, 0, stream>>>(
            xb, wqkvT, b_qkv, Qb, Kt, Vt, MROWS, NQKV, DMODEL);
        transpose_cast<<<dim3(DMODEL / 32, DMODEL / 32), 256, 0, stream>>>(w_proj, wprojT, DMODEL, DMODEL);
        attn_split<<<dim3(1024), 128, 0, stream>>>(Qb, Kt, Vt, attnb,
                                                   PO_a, PO_b, Pl_a, Pl_b);
        attn_combine<<<dim3(2048), 256, 0, stream>>>(PO_a, PO_b, Pl_a, Pl_b, attnb);
    } else {
        // fallback (small ws): V linear + transpose_v + paired attention.
        ushort_t* Vb    = (ushort_t*)(ws + 32505856);
        ushort_t* VtOld = (ushort_t*)(ws);
        gemm_glds<2, 4, 4><<<768, 256, 0, stream>>>(
            xb, wqkvT, b_qkv, Qb, Kt, Vb, MROWS, NQKV, DMODEL);
        transpose_v<<<dim3(32, 32), 256, 0, stream>>>(Vb, VtOld);
        transpose_cast<<<dim3(DMODEL / 32, DMODEL / 32), 256, 0, stream>>>(w_proj, wprojT, DMODEL, DMODEL);
        attn_paired<<<dim3(16, 32), 256, 0, stream>>>(Qb, Kt, VtOld, Vb);
        // attn_paired wrote attnb == Vb region
        gemm_glds<0, 2, 8><<<512, 256, 0, stream>>>(
            Vb, wprojT, b_proj, out, nullptr, nullptr, MROWS, DMODEL, DMODEL);
        return;
    }

    // proj: 64 m-tiles (MFRAG=2) -> PERXCD=8; 8 n-tiles; 512 blocks 1-D.
    gemm_glds<0, 2, 8><<<512, 256, 0, stream>>>(
        attnb, wprojT, b_proj, out, nullptr, nullptr, MROWS, DMODEL, DMODEL);
}

// Round 12
// 175.826 us; speedup vs baseline: 1.0511x; 1.0291x over previous
//
#include <hip/hip_runtime.h>
#include <hip/hip_bf16.h>
#include <stdint.h>

// Problem constants: x[2,2048,1024], H=16, Dh=64
#define MROWS 4096   // B*T
#define DMODEL 1024
#define NQKV 3072
#define TSEQ 2048

typedef __attribute__((ext_vector_type(8))) short short8;   // 8 bf16 = 4 VGPRs
typedef __attribute__((ext_vector_type(4))) short short4v;  // 4 bf16 = 2 VGPRs
typedef __attribute__((ext_vector_type(4))) float floatx4;  // MFMA C/D
typedef unsigned short ushort_t;

// K/V tiled layouts for glds staging: [bh][32 tiles][64 rows][72] bf16.
#define TILE_ELEMS 4608        // 64*72
#define BH_TILE_STRIDE 147456  // 32*4608

// Q pre-scale: (1/sqrt(64)) * log2(e) -- attention softmax runs in base 2.
#define QSCALE 0.1803368801111204f

static __device__ __forceinline__ unsigned short f2bf(float f) {
    union { float f; unsigned u; } v; v.f = f;
    unsigned r = v.u + 0x7fff + ((v.u >> 16) & 1);   // RNE
    return (unsigned short)(r >> 16);
}

// --- target-specific intrinsic wrappers -------------------------------------
// hipcc compiles this TU twice (device gfx950 + host x86). Host pass must
// PARSE device code but never executes it; gate amdgcn-only builtins on
// __HIP_DEVICE_COMPILE__ so the host pass gets plain-C fallbacks.

// D = A*B + C, 16x16x16 bf16 (A,B: 4 bf16/lane; C/D: 4 fp32/lane)
static __device__ __forceinline__ floatx4 mfma16(short4v a, short4v b, floatx4 c) {
#if defined(__HIP_DEVICE_COMPILE__)
#if __has_builtin(__builtin_amdgcn_mfma_f32_16x16x16bf16_1k)
    return __builtin_amdgcn_mfma_f32_16x16x16bf16_1k(a, b, c, 0, 0, 0);
#else
#error "mfma 16x16x16 bf16 builtin unavailable on device"
#endif
#else
    return c;   // host pass: parse-only, never executed
#endif
}

// pack two fp32 -> two bf16 (round-half-up): low16 = bf16(a), high16 = bf16(b).
static __device__ __forceinline__ unsigned pk2bf(float a, float b) {
    unsigned ua = __float_as_uint(a) + 0x8000u;
    unsigned ub = __float_as_uint(b) + 0x8000u;
#if defined(__HIP_DEVICE_COMPILE__) && __has_builtin(__builtin_amdgcn_perm)
    return __builtin_amdgcn_perm(ub, ua, 0x07060302u);  // {ub.b3,ub.b2,ua.b3,ua.b2}
#else
    return (ua >> 16) | (ub & 0xFFFF0000u);
#endif
}

// pack two fp32 -> two bf16 via the HW packed converter (RNE), 1 instr vs 3.
static __device__ __forceinline__ unsigned cvtpk(float a, float b) {
#if defined(__HIP_DEVICE_COMPILE__)
    unsigned r;
    asm("v_cvt_pk_bf16_f32 %0, %1, %2" : "=v"(r) : "v"(a), "v"(b));
    return r;
#else
    return pk2bf(a, b);   // host pass: parse-only
#endif
}

static __device__ __forceinline__ float exp2_fast(float x) {
#if defined(__HIP_DEVICE_COMPILE__) && __has_builtin(__builtin_amdgcn_exp2f)
    return __builtin_amdgcn_exp2f(x);
#else
    return exp2f(x);
#endif
}

// async global->LDS, 16B per lane. Global addr must be PER-LANE; LDS dest is
// wave-uniform base + lane*16.
static __device__ __forceinline__ void glds16(const void* g, void* l) {
    __builtin_amdgcn_global_load_lds(
        (const __attribute__((address_space(1))) void*)g,
        (__attribute__((address_space(3))) void*)l, 16, 0, 0);
}

// ---------------- cast fp32 -> bf16 (FALLBACK PATH, n multiple of 4) ---------
__global__ void cast_f32_bf16(const float* __restrict__ in,
                              ushort_t* __restrict__ out, int n) {
    int i = (blockIdx.x * blockDim.x + threadIdx.x) * 4;
    if (i < n) {
        float4 f = *(const float4*)(in + i);
        ushort4 o;
        o.x = f2bf(f.x); o.y = f2bf(f.y); o.z = f2bf(f.z); o.w = f2bf(f.w);
        *(ushort4*)(out + i) = o;
    }
}

// ---------------- transpose + cast (FALLBACK PATH): in[R][C] f32 -> out[C][R] bf16
__global__ void transpose_cast(const float* __restrict__ in,
                               ushort_t* __restrict__ out, int R, int C) {
    __shared__ float tile[32][33];
    int c0 = blockIdx.x * 32, r0 = blockIdx.y * 32;
    int tx = threadIdx.x & 31, ty = threadIdx.x >> 5;
    for (int i = 0; i < 4; i++) {
        int r = ty + i * 8;
        tile[r][tx] = in[(size_t)(r0 + r) * C + c0 + tx];
    }
    __syncthreads();
    for (int i = 0; i < 4; i++) {
        int r = ty + i * 8;
        out[(size_t)(c0 + r) * R + r0 + tx] = f2bf(tile[tx][r]);
    }
}

// ---------------- fused prep: cast x->xb + transpose wqkv + transpose wproj --
// One 8192-block launch, block-uniform range dispatch, replaces 3 launches.
// ROUND-12 FIX: round-11 failed because wprojT aliased wqkvT (that aliasing
// was only safe in the OLD ordering where wprojT was written after the QKV
// GEMM killed wqkvT). Main path now gives wprojT dedicated space; all three
// outputs (xb, wqkvT, wprojT) are pairwise disjoint.
__global__ void prep_fused(const float* __restrict__ x, ushort_t* __restrict__ xb,
                           const float* __restrict__ w_qkv, ushort_t* __restrict__ wqkvT,
                           const float* __restrict__ w_proj, ushort_t* __restrict__ wprojT) {
    __shared__ float tile[32][33];
    int id = blockIdx.x;
    if (id < 4096) {
        // cast x (f32) -> xb (bf16), 4 elems/thread; 4096 blocks x 1024 elems
        int i = (id * 256 + threadIdx.x) * 4;
        float4 f = *(const float4*)(x + i);
        ushort4 o;
        o.x = f2bf(f.x); o.y = f2bf(f.y); o.z = f2bf(f.z); o.w = f2bf(f.w);
        *(ushort4*)(xb + i) = o;
        return;
    }
    // transpose+cast: in[.][C] f32 -> out[C][R] bf16
    const float* in; ushort_t* out; int C, R, bx, by;
    if (id < 4096 + 3072) {
        int t = id - 4096;                 // wqkv: old grid (96, 32)
        in = w_qkv; out = wqkvT; R = DMODEL; C = NQKV;
        bx = t % 96; by = t / 96;
    } else {
        int t = id - 7168;                 // wproj: old grid (32, 32)
        in = w_proj; out = wprojT; R = DMODEL; C = DMODEL;
        bx = t & 31; by = t >> 5;
    }
    int c0 = bx * 32, r0 = by * 32;
    int tx = threadIdx.x & 31, ty = threadIdx.x >> 5;
    for (int i = 0; i < 4; i++) {
        int r = ty + i * 8;
        tile[r][tx] = in[(size_t)(r0 + r) * C + c0 + tx];
    }
    __syncthreads();
    for (int i = 0; i < 4; i++) {
        int r = ty + i * 8;
        out[(size_t)(c0 + r) * R + r0 + tx] = f2bf(tile[tx][r]);
    }
}

// ---------------- V transpose (FALLBACK PATH ONLY): Vb -> Vt tiled ----------
__global__ void transpose_v(const ushort_t* __restrict__ in,
                            ushort_t* __restrict__ out) {
    __shared__ ushort_t T[64][72];
    int tile = blockIdx.x, bh = blockIdx.y;
    int tid = threadIdx.x;
    int row = tid >> 2, q4 = tid & 3;
    const ushort_t* ip = in + ((size_t)bh * TSEQ + tile * 64) * 64;
#pragma unroll
    for (int p = 0; p < 2; p++) {
        int c = q4 * 16 + p * 8;
        *(uint4*)(&T[row][c]) = *(const uint4*)(ip + (size_t)row * 64 + c);
    }
    __syncthreads();
    ushort_t* op = out + (size_t)bh * BH_TILE_STRIDE + (size_t)tile * TILE_ELEMS;
#pragma unroll
    for (int p = 0; p < 2; p++) {
        int cbase = q4 * 16 + p * 8;          // c' chunk base
        ushort_t tmp[8];
#pragma unroll
        for (int e = 0; e < 8; e++) {
            int cp = cbase + e;               // c' = 16*Q + 4*SB + J
            int Q = cp >> 4, SB = (cp >> 2) & 3, J = cp & 3;
            int s = SB * 16 + Q * 4 + J;
            tmp[e] = T[s][row];               // row = d
        }
        *(uint4*)(op + (size_t)row * 72 + cbase) = *(uint4*)tmp;
    }
}

// ---------------- GEMM (dbuf 2-phase, BK=32), XCD-swizzled 1-D grid ----------
// C = A[M][K] @ Bt[N][K]^T + bias.  (round-6 proven version, 180.7 us x3)
// T3-minimum recipe: double-buffered LDS, prefetch of tile k+32 ISSUED BEFORE
// the ds_read+MFMA of tile k, single __syncthreads per K-step. Structural
// floor for the 128-tile shape at these problem dims (rounds 7/8 falsified
// swizzle and deeper pipelining).
// Block mapping: id -> xcd = id&7, each XCD owns PERXCD consecutive m-tiles.
// EPI 0: fp32 out0[M][N] + bias.
// EPI 1: Q -> [bh][t][64] bf16 *QSCALE; K -> tiled; V -> tiled-permuted direct.
// EPI 2: like EPI 1 but V linear (fallback, feeds transpose_v).
template <int EPI, int MFRAG, int PERXCD>
__global__ __launch_bounds__(256, 3)
void gemm_glds(const ushort_t* __restrict__ A,
               const ushort_t* __restrict__ Bt,
               const float* __restrict__ bias,
               void* __restrict__ out0, void* __restrict__ out1, void* __restrict__ out2,
               int M, int N, int K) {
    __shared__ ushort_t As[2][MFRAG * 32 * 32];
    __shared__ ushort_t Bs[2][128 * 32];
    int tid = threadIdx.x;
    int wave = tid >> 6, lane = tid & 63;
    int quad = lane >> 4, l16 = lane & 15;
    // XCD swizzle (PERXCD is a power of two)
    int id = blockIdx.x;
    int xcd = id & 7, sidx = id >> 3;
    int m_idx = xcd * PERXCD + (sidx & (PERXCD - 1));
    int n_idx = sidx / PERXCD;
    int m0 = m_idx * (MFRAG * 32), n0 = n_idx * 128;
    int wm = (wave & 1) * (MFRAG * 16), wn = (wave >> 1) * 64;

    const floatx4 zero = {0.f, 0.f, 0.f, 0.f};
    floatx4 acc[MFRAG][4];
#pragma unroll
    for (int i = 0; i < MFRAG; i++)
#pragma unroll
        for (int j = 0; j < 4; j++) acc[i][j] = zero;

    int srow = tid >> 2, sc = tid & 3;
    const ushort_t* ag = A  + (size_t)(m0 + srow) * K + sc * 8;
    const ushort_t* bg = Bt + (size_t)(n0 + srow) * K + sc * 8;
    int woff = wave * 512;

    // prologue: stage tile 0 into buffer 0, drain, then loop with prefetch
    glds16(ag, &As[0][woff]);
    if (MFRAG == 4) glds16(ag + (size_t)64 * K, &As[0][woff + 2048]);
    glds16(bg, &Bs[0][woff]);
    glds16(bg + (size_t)64 * K, &Bs[0][woff + 2048]);
    __syncthreads();

    int cur = 0;
    for (int k0 = 0; k0 < K; k0 += 32) {
        if (k0 + 32 < K) {
            int nb = cur ^ 1, kn = k0 + 32;
            glds16(ag + kn, &As[nb][woff]);
            if (MFRAG == 4) glds16(ag + (size_t)64 * K + kn, &As[nb][woff + 2048]);
            glds16(bg + kn, &Bs[nb][woff]);
            glds16(bg + (size_t)64 * K + kn, &Bs[nb][woff + 2048]);
        }
        short8 af[MFRAG], bf[4];
#pragma unroll
        for (int i = 0; i < MFRAG; i++)
            af[i] = *(const short8*)(&As[cur][(wm + i * 16 + l16) * 32 + quad * 8]);
#pragma unroll
        for (int j = 0; j < 4; j++)
            bf[j] = *(const short8*)(&Bs[cur][(wn + j * 16 + l16) * 32 + quad * 8]);
#pragma unroll
        for (int i = 0; i < MFRAG; i++)
#pragma unroll
            for (int j = 0; j < 4; j++)
                acc[i][j] = __builtin_amdgcn_mfma_f32_16x16x32_bf16(
                    af[i], bf[j], acc[i][j], 0, 0, 0);
        __syncthreads();   // emits vmcnt(0) lgkmcnt(0): prefetch has had
        cur ^= 1;          // the whole MFMA block to land
    }

    int sec = n0 >> 10;   // block-uniform (EPI!=0): 0=Q, 1=K, 2=V
    ushort_t* dst = (ushort_t*)(sec == 0 ? out0 : (sec == 1 ? out1 : out2));

    if (EPI == 1 && sec == 2) {
        // V -> tiled-permuted Vt, one 8B store per fragment
#pragma unroll
        for (int i = 0; i < MFRAG; i++) {
            int row = m0 + wm + i * 16 + quad * 4;
            int Abits = ((wm >> 4) + i) & 3;        // SB of s = t_local
            int b = row >> 11, t = row & 2047;
            int tile = t >> 6;
            int colp = 16 * quad + 4 * Abits;       // col' base; r adds 0..3
#pragma unroll
            for (int j = 0; j < 4; j++) {
                int col = n0 + wn + j * 16 + l16;
                int within = col & 1023, h = within >> 6, d = within & 63;
                size_t bh = (size_t)(b * 16 + h);
                float bvs = bias[col];
                ushort4 o;
                o.x = f2bf(acc[i][j][0] + bvs);
                o.y = f2bf(acc[i][j][1] + bvs);
                o.z = f2bf(acc[i][j][2] + bvs);
                o.w = f2bf(acc[i][j][3] + bvs);
                *(ushort4*)(dst + bh * BH_TILE_STRIDE + (size_t)tile * TILE_ELEMS
                            + (size_t)d * 72 + colp) = o;
            }
        }
        return;
    }

#pragma unroll
    for (int i = 0; i < MFRAG; i++) {
        int row = m0 + wm + i * 16 + quad * 4;
#pragma unroll
        for (int j = 0; j < 4; j++) {
            int col = n0 + wn + j * 16 + l16;
            float bvs = bias[col];
#pragma unroll
            for (int r = 0; r < 4; r++) {
                float v = acc[i][j][r] + bvs;
                int rowr = row + r;
                if (EPI == 0) {
                    ((float*)out0)[(size_t)rowr * N + col] = v;
                } else {
                    int b = rowr >> 11, t = rowr & 2047;
                    int within = col & 1023, h = within >> 6, d = within & 63;
                    size_t bh = (size_t)(b * 16 + h);
                    if (sec == 0)
                        dst[(bh * 2048 + t) * 64 + d] = f2bf(v * QSCALE);
                    else if (sec == 1)
                        dst[bh * BH_TILE_STRIDE + (size_t)(t >> 6) * TILE_ELEMS
                            + (size_t)(t & 63) * 72 + d] = f2bf(v);
                    else
                        dst[(bh * 2048 + t) * 64 + d] = f2bf(v);   // EPI==2 linear V
                }
            }
        }
    }
}

// ---------------- flash attention, key-split uniform blocks, 2-wave ----------
// Round-6 proven version (180.7 us x3). 2 waves x 32 q-rows; each K/V LDS
// fragment read once per wave, reused for two q-slices.
// Q: [bh][t][64] (pre-scaled by QSCALE). Kt/Vt: [bh][32][64][72] tiled
// (Vt column-permuted). out: [b*2048+t][h*64+d] bf16.
// Base-2 softmax, no max-shift: partials merge by addition -> key-split:
//   sub0 (17 steps): q-tile p keys 0..p -> final bf16; + q-tile 31-p keys
//   0..15-p -> fp32 partial A.  sub1 (16 steps): keys 16-p..31-p -> partial B.
// attn_combine does (O_A+O_B)/(l_A+l_B) for the upper 1024 rows.
// XCD-affine: id&7 -> XCD, 4 bh per XCD (K/V L2-resident; FETCH 139->13 MB).
__global__ __launch_bounds__(128, 2)
void attn_split(const ushort_t* __restrict__ Qb,
                const ushort_t* __restrict__ Kt,
                const ushort_t* __restrict__ Vt,
                ushort_t* __restrict__ outb,
                float* __restrict__ PO_a, float* __restrict__ PO_b,
                float* __restrict__ Pl_a, float* __restrict__ Pl_b) {
    __shared__ ushort_t Ks[2][64 * 72];
    __shared__ ushort_t Vs[2][64 * 72];
    int tid = threadIdx.x;
    int wave = tid >> 6, lane = tid & 63;   // wave 0..1
    int quad = lane >> 4, l16 = lane & 15;
    int id = blockIdx.x;                  // 0..1023
    int g = id >> 3;                      // 0..127
    int bh = (id & 7) * 4 + (g >> 5);     // XCD-affine: id&7 -> XCD, 4 bh/XCD
    int rem = g & 31;
    int p = rem >> 1, sub = rem & 1;      // pair 0..15, sub-block 0/1
    int b = bh >> 4, h = bh & 15;
    const ushort_t* qh = Qb + (size_t)bh * TSEQ * 64;
    const ushort_t* kh = Kt + (size_t)bh * BH_TILE_STRIDE;
    const ushort_t* vh = Vt + (size_t)bh * BH_TILE_STRIDE;
    const floatx4 zero = {0.f, 0.f, 0.f, 0.f};
    const short4v ones = {(short)0x3F80, (short)0x3F80, (short)0x3F80, (short)0x3F80};
    int lo8 = lane * 8;   // per-lane 16B offset for glds global addresses

    int nseg = sub ? 1 : 2;
    for (int seg = 0; seg < nseg; seg++) {
        int qt, k0, cnt, mode;   // mode: 0=direct bf16, 1=partial A, 2=partial B
        if (sub)           { qt = 31 - p; k0 = 16 - p; cnt = 16;     mode = 2; }
        else if (seg == 0) { qt = p;      k0 = 0;      cnt = p + 1;  mode = 0; }
        else               { qt = 31 - p; k0 = 0;      cnt = 16 - p; mode = 1; }

        // Q fragments for the wave's TWO 16-row q-slices; B-operand (n=l16).
        short8 qf0[2], qf1[2];
#pragma unroll
        for (int qs = 0; qs < 2; qs++) {
            int qrow = qt * 64 + wave * 32 + qs * 16 + l16;
            qf0[qs] = *(const short8*)(qh + (size_t)qrow * 64 + quad * 8);
            qf1[qs] = *(const short8*)(qh + (size_t)qrow * 64 + 32 + quad * 8);
        }

        floatx4 Oacc[2][4];
#pragma unroll
        for (int qs = 0; qs < 2; qs++)
#pragma unroll
            for (int j = 0; j < 4; j++) Oacc[qs][j] = zero;
        floatx4 lacc[2];
        lacc[0] = zero; lacc[1] = zero;

        // all waves done reading previous segment's buffers before reuse
        __syncthreads();
        // preload tile k0 -> buffer 0 (9 KB each = 9 x 1KB glds, 2 waves)
        {
            const ushort_t* kt0 = kh + (size_t)k0 * TILE_ELEMS;
            const ushort_t* vt0 = vh + (size_t)k0 * TILE_ELEMS;
#pragma unroll
            for (int c = 0; c < 5; c++) {
                int cc = wave + 2 * c;
                if (cc < 9) {
                    glds16(kt0 + cc * 512 + lo8, &Ks[0][cc * 512]);
                    glds16(vt0 + cc * 512 + lo8, &Vs[0][cc * 512]);
                }
            }
        }

        for (int step = 0; step < cnt; step++) {
            int cur = step & 1;
            __syncthreads();
            if (step + 1 < cnt) {
                const ushort_t* kt = kh + (size_t)(k0 + step + 1) * TILE_ELEMS;
                const ushort_t* vt = vh + (size_t)(k0 + step + 1) * TILE_ELEMS;
#pragma unroll
                for (int c = 0; c < 5; c++) {
                    int cc = wave + 2 * c;
                    if (cc < 9) {
                        glds16(kt + cc * 512 + lo8, &Ks[cur ^ 1][cc * 512]);
                        glds16(vt + cc * 512 + lo8, &Vs[cur ^ 1][cc * 512]);
                    }
                }
            }
            const ushort_t* ks = &Ks[cur][0];
            const ushort_t* vs = &Vs[cur][0];

            // S^T = K Q^T : K-frag read ONCE per sb, used for both q-slices.
            floatx4 S[2][4];
            __builtin_amdgcn_s_setprio(1);
#pragma unroll
            for (int sb = 0; sb < 4; sb++) {
                short8 kf0 = *(const short8*)(ks + (sb * 16 + l16) * 72 + quad * 8);
                short8 kf1 = *(const short8*)(ks + (sb * 16 + l16) * 72 + 32 + quad * 8);
#pragma unroll
                for (int qs = 0; qs < 2; qs++) {
                    floatx4 s = zero;
                    s = __builtin_amdgcn_mfma_f32_16x16x32_bf16(kf0, qf0[qs], s, 0, 0, 0);
                    s = __builtin_amdgcn_mfma_f32_16x16x32_bf16(kf1, qf1[qs], s, 0, 0, 0);
                    S[qs][sb] = s;
                }
            }
            __builtin_amdgcn_s_setprio(0);
            // causal mask only on the true diagonal tile (k0+step == qt)
            if (k0 + step == qt) {
#pragma unroll
                for (int qs = 0; qs < 2; qs++) {
                    int ql = wave * 32 + qs * 16 + l16;
#pragma unroll
                    for (int sb = 0; sb < 4; sb++)
#pragma unroll
                        for (int r = 0; r < 4; r++)
                            if (sb * 16 + quad * 4 + r > ql) S[qs][sb][r] = -1e30f;
                }
            }
            // p = 2^s (log2e folded into Q scale); 2^(-1e30) == 0 for masked
#pragma unroll
            for (int qs = 0; qs < 2; qs++)
#pragma unroll
                for (int sb = 0; sb < 4; sb++)
#pragma unroll
                    for (int r = 0; r < 4; r++)
                        S[qs][sb][r] = exp2_fast(S[qs][sb][r]);

            // P^T B-frags via packed HW converter
            short4v pf[2][4];
#pragma unroll
            for (int qs = 0; qs < 2; qs++)
#pragma unroll
                for (int sb = 0; sb < 4; sb++) {
                    union { unsigned u[2]; short4v v; } pk;
                    pk.u[0] = cvtpk(S[qs][sb][0], S[qs][sb][1]);
                    pk.u[1] = cvtpk(S[qs][sb][2], S[qs][sb][3]);
                    pf[qs][sb] = pk.v;
                }
            __builtin_amdgcn_s_setprio(1);
            // l accumulation: ones-row MFMA, two independent chains
#pragma unroll
            for (int qs = 0; qs < 2; qs++) {
                lacc[qs] = mfma16(ones, pf[qs][0], lacc[qs]);
                lacc[qs] = mfma16(ones, pf[qs][1], lacc[qs]);
                lacc[qs] = mfma16(ones, pf[qs][2], lacc[qs]);
                lacc[qs] = mfma16(ones, pf[qs][3], lacc[qs]);
            }
            // O^T += V^T P^T : V-frag read ONCE per d-tile, used for both qs.
#pragma unroll
            for (int jd = 0; jd < 4; jd++) {
                const ushort_t* vrow = vs + (jd * 16 + l16) * 72 + quad * 16;
                short8 vA = *(const short8*)(vrow);       // sb0 | sb1
                short8 vB = *(const short8*)(vrow + 8);   // sb2 | sb3
                short4v v0 = __builtin_shufflevector(vA, vA, 0, 1, 2, 3);
                short4v v1 = __builtin_shufflevector(vA, vA, 4, 5, 6, 7);
                short4v v2 = __builtin_shufflevector(vB, vB, 0, 1, 2, 3);
                short4v v3 = __builtin_shufflevector(vB, vB, 4, 5, 6, 7);
#pragma unroll
                for (int qs = 0; qs < 2; qs++) {
                    Oacc[qs][jd] = mfma16(v0, pf[qs][0], Oacc[qs][jd]);
                    Oacc[qs][jd] = mfma16(v1, pf[qs][1], Oacc[qs][jd]);
                    Oacc[qs][jd] = mfma16(v2, pf[qs][2], Oacc[qs][jd]);
                    Oacc[qs][jd] = mfma16(v3, pf[qs][3], Oacc[qs][jd]);
                }
            }
            __builtin_amdgcn_s_setprio(0);
        }

        if (mode == 0) {
            // full row of keys seen: normalize and store final bf16
#pragma unroll
            for (int qs = 0; qs < 2; qs++) {
                float rl = 1.0f / lacc[qs][0];
                int row = b * TSEQ + qt * 64 + wave * 32 + qs * 16 + l16;
#pragma unroll
                for (int jd = 0; jd < 4; jd++) {
                    int col = h * 64 + jd * 16 + quad * 4;
                    ushort4 o;
                    o.x = f2bf(Oacc[qs][jd][0] * rl);
                    o.y = f2bf(Oacc[qs][jd][1] * rl);
                    o.z = f2bf(Oacc[qs][jd][2] * rl);
                    o.w = f2bf(Oacc[qs][jd][3] * rl);
                    *(ushort4*)(outb + (size_t)row * DMODEL + col) = o;
                }
            }
        } else {
            // fp32 partial: [bh][prow][64] O and [bh][prow] l (upper q-tiles only)
            float* PO = (mode == 1) ? PO_a : PO_b;
            float* Pl = (mode == 1) ? Pl_a : Pl_b;
#pragma unroll
            for (int qs = 0; qs < 2; qs++) {
                int prow = (qt - 16) * 64 + wave * 32 + qs * 16 + l16;
                size_t rbase = ((size_t)bh * 1024 + prow) * 64;
#pragma unroll
                for (int jd = 0; jd < 4; jd++)
                    *(floatx4*)(PO + rbase + jd * 16 + quad * 4) = Oacc[qs][jd];
                if (quad == 0) Pl[(size_t)bh * 1024 + prow] = lacc[qs][0];
            }
        }
    }
}

// combine upper-half rows: out = (O_A + O_B) / (l_A + l_B) -> bf16
__global__ void attn_combine(const float* __restrict__ PO_a,
                             const float* __restrict__ PO_b,
                             const float* __restrict__ Pl_a,
                             const float* __restrict__ Pl_b,
                             ushort_t* __restrict__ outb) {
    int i = blockIdx.x * 256 + threadIdx.x;
    int row = i >> 4;             // bh*1024 + prow
    int c4 = (i & 15) * 4;        // col within head
    float rl = 1.0f / (Pl_a[row] + Pl_b[row]);
    floatx4 a = *(const floatx4*)(PO_a + (size_t)row * 64 + c4);
    floatx4 c = *(const floatx4*)(PO_b + (size_t)row * 64 + c4);
    int bh = row >> 10, prow = row & 1023;
    int b = bh >> 4, h = bh & 15;
    int orow = b * TSEQ + 1024 + prow;
    ushort4 o;
    o.x = f2bf((a[0] + c[0]) * rl);
    o.y = f2bf((a[1] + c[1]) * rl);
    o.z = f2bf((a[2] + c[2]) * rl);
    o.w = f2bf((a[3] + c[3]) * rl);
    *(ushort4*)(outb + (size_t)orow * DMODEL + h * 64 + c4) = o;
}

// ---------------- fallback: paired attention ----------
__global__ __launch_bounds__(256, 1)
void attn_paired(const ushort_t* __restrict__ Qb,
                 const ushort_t* __restrict__ Kt,
                 const ushort_t* __restrict__ Vt,
                 ushort_t* __restrict__ outb) {
    __shared__ ushort_t Ks[2][64 * 72];
    __shared__ ushort_t Vs[2][64 * 72];
    int tid = threadIdx.x;
    int wave = tid >> 6, lane = tid & 63;
    int quad = lane >> 4, l16 = lane & 15;
    int pair = blockIdx.x;   // 0..15
    int bh = blockIdx.y;     // 0..31
    int b = bh >> 4, h = bh & 15;
    const ushort_t* qh = Qb + (size_t)bh * TSEQ * 64;
    const ushort_t* kh = Kt + (size_t)bh * BH_TILE_STRIDE;
    const ushort_t* vh = Vt + (size_t)bh * BH_TILE_STRIDE;
    const floatx4 zero = {0.f, 0.f, 0.f, 0.f};
    int lo8 = lane * 8;

    for (int half = 0; half < 2; half++) {
        int qt = half ? (31 - pair) : pair;
        int q0 = qt * 64;
        int nsteps = qt + 1;

        int qrow = q0 + wave * 16 + l16;
        short8 qf0 = *(const short8*)(qh + (size_t)qrow * 64 + quad * 8);
        short8 qf1 = *(const short8*)(qh + (size_t)qrow * 64 + 32 + quad * 8);

        floatx4 Oacc[4];
#pragma unroll
        for (int j = 0; j < 4; j++) Oacc[j] = zero;
        float lsum = 0.f;

#pragma unroll
        for (int c = 0; c < 3; c++) {
            int cc = wave + 4 * c;
            if (cc < 9) {
                glds16(kh + cc * 512 + lo8, &Ks[0][cc * 512]);
                glds16(vh + cc * 512 + lo8, &Vs[0][cc * 512]);
            }
        }

        for (int step = 0; step < nsteps; step++) {
            int cur = step & 1;
            __syncthreads();
            if (step + 1 < nsteps) {
                const ushort_t* kt = kh + (size_t)(step + 1) * TILE_ELEMS;
                const ushort_t* vt = vh + (size_t)(step + 1) * TILE_ELEMS;
#pragma unroll
                for (int c = 0; c < 3; c++) {
                    int cc = wave + 4 * c;
                    if (cc < 9) {
                        glds16(kt + cc * 512 + lo8, &Ks[cur ^ 1][cc * 512]);
                        glds16(vt + cc * 512 + lo8, &Vs[cur ^ 1][cc * 512]);
                    }
                }
            }
            const ushort_t* ks = &Ks[cur][0];
            const ushort_t* vs = &Vs[cur][0];

            floatx4 S[4];
#pragma unroll
            for (int sb = 0; sb < 4; sb++) {
                short8 kf0 = *(const short8*)(ks + (sb * 16 + l16) * 72 + quad * 8);
                short8 kf1 = *(const short8*)(ks + (sb * 16 + l16) * 72 + 32 + quad * 8);
                floatx4 s = zero;
                s = __builtin_amdgcn_mfma_f32_16x16x32_bf16(kf0, qf0, s, 0, 0, 0);
                s = __builtin_amdgcn_mfma_f32_16x16x32_bf16(kf1, qf1, s, 0, 0, 0);
                S[sb] = s;
            }
            if (step == nsteps - 1) {
                int ql = wave * 16 + l16;
#pragma unroll
                for (int sb = 0; sb < 4; sb++)
#pragma unroll
                    for (int r = 0; r < 4; r++)
                        if (sb * 16 + quad * 4 + r > ql) S[sb][r] = -1e30f;
            }
            float sum = 0.f;
#pragma unroll
            for (int sb = 0; sb < 4; sb++)
#pragma unroll
                for (int r = 0; r < 4; r++) {
                    float p = exp2_fast(S[sb][r]);
                    S[sb][r] = p;
                    sum += p;
                }
            lsum += sum;

            short4v pf[4];
#pragma unroll
            for (int sb = 0; sb < 4; sb++) {
                union { unsigned u[2]; short4v v; } pk;
                pk.u[0] = pk2bf(S[sb][0], S[sb][1]);
                pk.u[1] = pk2bf(S[sb][2], S[sb][3]);
                pf[sb] = pk.v;
            }
#pragma unroll
            for (int jd = 0; jd < 4; jd++) {
                const ushort_t* vrow = vs + (jd * 16 + l16) * 72 + quad * 16;
                short8 vA = *(const short8*)(vrow);
                short8 vB = *(const short8*)(vrow + 8);
                short4v v0 = __builtin_shufflevector(vA, vA, 0, 1, 2, 3);
                short4v v1 = __builtin_shufflevector(vA, vA, 4, 5, 6, 7);
                short4v v2 = __builtin_shufflevector(vB, vB, 0, 1, 2, 3);
                short4v v3 = __builtin_shufflevector(vB, vB, 4, 5, 6, 7);
                Oacc[jd] = mfma16(v0, pf[0], Oacc[jd]);
                Oacc[jd] = mfma16(v1, pf[1], Oacc[jd]);
                Oacc[jd] = mfma16(v2, pf[2], Oacc[jd]);
                Oacc[jd] = mfma16(v3, pf[3], Oacc[jd]);
            }
        }
        {
            float l = lsum;
            l += __shfl_xor(l, 16);
            l += __shfl_xor(l, 32);
            float rl = 1.0f / l;
            int row = b * TSEQ + q0 + wave * 16 + l16;
#pragma unroll
            for (int jd = 0; jd < 4; jd++) {
                int col = h * 64 + jd * 16 + quad * 4;
                ushort4 o;
                o.x = f2bf(Oacc[jd][0] * rl);
                o.y = f2bf(Oacc[jd][1] * rl);
                o.z = f2bf(Oacc[jd][2] * rl);
                o.w = f2bf(Oacc[jd][3] * rl);
                *(ushort4*)(outb + (size_t)row * DMODEL + col) = o;
            }
        }
        __syncthreads();
    }
}

extern "C" void kernel_launch(void* const* d_in, const int* in_sizes, int n_in,
                              void* d_out, int out_size, void* d_ws, size_t ws_size,
                              hipStream_t stream) {
    const float* x      = (const float*)d_in[0];
    const float* w_qkv  = (const float*)d_in[1];
    const float* b_qkv  = (const float*)d_in[2];
    const float* w_proj = (const float*)d_in[3];
    const float* b_proj = (const float*)d_in[4];
    float* out = (float*)d_out;
    char* ws = (char*)d_ws;

    // workspace (main path, ~69.5 MB). ALIAS AUDIT: all regions pairwise
    // disjoint; every buffer has one writer phase preceding all readers.
    //  [0,8M):          xb (x bf16)
    //  [8388608,+6M):   wqkvT (dead after QKV GEMM)
    //  [14680064,+8M):  Qb   [bh][2048][64]
    //  [23068672,+9M):  Kt   [bh][32][64][72] tiled
    //  [32505856,+8M):  attnb (attn output rows)
    //  [40894464,+9M):  Vt   [bh][32][64][72] tiled-permuted (GEMM-direct)
    //  [50331648,+8M):  PO_a fp32 partial O
    //  [58720256,+8M):  PO_b fp32 partial O
    //  [67108864,128K): Pl_a; [67239936,128K): Pl_b
    //  [67371008,+2M):  wprojT  (DEDICATED -- round-11 aliased it into wqkvT
    //                   while fusing prep, which clobbered live weights)
    ushort_t* xb     = (ushort_t*)(ws);
    ushort_t* wqkvT  = (ushort_t*)(ws + 8388608);
    ushort_t* Qb     = (ushort_t*)(ws + 14680064);
    ushort_t* Kt     = (ushort_t*)(ws + 23068672);
    ushort_t* attnb  = (ushort_t*)(ws + 32505856);
    ushort_t* Vt     = (ushort_t*)(ws + 40894464);
    float* PO_a = (float*)(ws + 50331648);
    float* PO_b = (float*)(ws + 58720256);
    float* Pl_a = (float*)(ws + 67108864);
    float* Pl_b = (float*)(ws + 67239936);
    ushort_t* wprojT = (ushort_t*)(ws + 67371008);
    const size_t ws_need = 69468160;

    if (ws_size >= ws_need) {
        // fused prep: cast x->xb + transpose wqkv + transpose wproj (1 launch)
        prep_fused<<<8192, 256, 0, stream>>>(x, xb, w_qkv, wqkvT, w_proj, wprojT);
        // QKV: V written tiled-permuted directly (no transpose_v pass).
        gemm_glds<1, 4, 4><<<768, 256, 0, stream>>>(
            xb, wqkvT, b_qkv, Qb, Kt, Vt, MROWS, NQKV, DMODEL);
        attn_split<<<dim3(1024), 128, 0, stream>>>(Qb, Kt, Vt, attnb,
                                                   PO_a, PO_b, Pl_a, Pl_b);
        attn_combine<<<dim3(2048), 256, 0, stream>>>(PO_a, PO_b, Pl_a, Pl_b, attnb);
        // proj: 64 m-tiles (MFRAG=2) -> PERXCD=8; 8 n-tiles; 512 blocks 1-D.
        gemm_glds<0, 2, 8><<<512, 256, 0, stream>>>(
            attnb, wprojT, b_proj, out, nullptr, nullptr, MROWS, DMODEL, DMODEL);
    } else {
        // fallback (small ws): round-10 proven sequence. wprojT aliases dead
        // wqkvT (at +10M) and is written AFTER the QKV GEMM -- safe here.
        ushort_t* wprojLo = (ushort_t*)(ws + 10485760);
        ushort_t* Vb      = (ushort_t*)(ws + 32505856);
        ushort_t* VtOld   = (ushort_t*)(ws);
        cast_f32_bf16<<<4096, 256, 0, stream>>>(x, xb, MROWS * DMODEL);
        transpose_cast<<<dim3(NQKV / 32, DMODEL / 32), 256, 0, stream>>>(w_qkv, wqkvT, DMODEL, NQKV);
        gemm_glds<2, 4, 4><<<768, 256, 0, stream>>>(
            xb, wqkvT, b_qkv, Qb, Kt, Vb, MROWS, NQKV, DMODEL);
        transpose_v<<<dim3(32, 32), 256, 0, stream>>>(Vb, VtOld);
        transpose_cast<<<dim3(DMODEL / 32, DMODEL / 32), 256, 0, stream>>>(w_proj, wprojLo, DMODEL, DMODEL);
        attn_paired<<<dim3(16, 32), 256, 0, stream>>>(Qb, Kt, VtOld, Vb);
        // attn_paired wrote attnb == Vb region
        gemm_glds<0, 2, 8><<<512, 256, 0, stream>>>(
            Vb, wprojLo, b_proj, out, nullptr, nullptr, MROWS, DMODEL, DMODEL);
    }
}